// Round 1
// baseline (2119.198 us; speedup 1.0000x reference)
//
#include <hip/hip_runtime.h>
#include <math.h>

#define N_NODES 50000
#define N_EDGES 800000
#define IN_DIM 128

// ---------------- helpers: order-preserving float<->uint for atomicMax ----------------
__device__ inline unsigned fkey(float f) {
  unsigned u = __float_as_uint(f);
  return (u & 0x80000000u) ? ~u : (u | 0x80000000u);
}
__device__ inline float fdecode(unsigned k) {
  return (k & 0x80000000u) ? __uint_as_float(k ^ 0x80000000u) : __uint_as_float(~k);
}

// ---------------- GEMM: C[M,N] = A[M,K] @ W[K,N] + bias ----------------
// BM=128, BK=16, BN=TN*16, block=256 threads, micro-tile 8 x TN per thread.
template <int TN>
__global__ void linear_kernel(const float* __restrict__ A, const float* __restrict__ W,
                              const float* __restrict__ bias, float* __restrict__ C,
                              int M, int K, int N) {
  constexpr int BM = 128, BK = 16;
  constexpr int BN = TN * 16;
  __shared__ float As[BK][BM + 4];
  __shared__ float Bs[BK][BN + 4];
  const int bm = blockIdx.x * BM;
  const int bn = blockIdx.y * BN;
  const int tid = threadIdx.x;       // 256 threads
  const int tx = tid % 16;           // 16 col-groups
  const int ty = tid / 16;           // 16 row-groups (8 rows each)

  float acc[8][TN];
#pragma unroll
  for (int i = 0; i < 8; ++i)
#pragma unroll
    for (int j = 0; j < TN; ++j) acc[i][j] = 0.f;

  for (int k0 = 0; k0 < K; k0 += BK) {
    // A tile: BM x BK = 2048 elems, 8 passes of 256
#pragma unroll
    for (int p = 0; p < 8; ++p) {
      int ml = tid / 16 + p * 16;
      int kk = tid % 16;
      int m = bm + ml;
      As[kk][ml] = (m < M) ? A[(size_t)m * K + k0 + kk] : 0.f;
    }
    // B tile: BK x BN elems
#pragma unroll
    for (int p = 0; p < (BK * BN) / 256; ++p) {
      int idx = tid + p * 256;
      int kk = idx / BN;
      int nl = idx % BN;
      int n = bn + nl;
      Bs[kk][nl] = (n < N) ? W[(size_t)(k0 + kk) * N + n] : 0.f;
    }
    __syncthreads();
#pragma unroll
    for (int kk = 0; kk < BK; ++kk) {
      float a[8], bb[TN];
#pragma unroll
      for (int i = 0; i < 8; ++i) a[i] = As[kk][ty * 8 + i];
#pragma unroll
      for (int j = 0; j < TN; ++j) bb[j] = Bs[kk][tx * TN + j];
#pragma unroll
      for (int i = 0; i < 8; ++i)
#pragma unroll
        for (int j = 0; j < TN; ++j) acc[i][j] += a[i] * bb[j];
    }
    __syncthreads();
  }
#pragma unroll
  for (int i = 0; i < 8; ++i) {
    int m = bm + ty * 8 + i;
    if (m >= M) continue;
#pragma unroll
    for (int j = 0; j < TN; ++j) {
      int n = bn + tx * TN + j;
      if (n < N) C[(size_t)m * N + n] = acc[i][j] + bias[n];
    }
  }
}

// ---------------- conv1 edge kernels (4 heads x 32 dims = 128) ----------------
// 32 lanes per edge; lane holds 4 contiguous floats (one head spans 8 lanes).
__global__ void edge_logits1(const int* __restrict__ ei, const float* __restrict__ Q,
                             const float* __restrict__ Kf, float* __restrict__ LG,
                             unsigned* __restrict__ Mx, int E) {
  int g = (blockIdx.x * blockDim.x + threadIdx.x) >> 5;
  int lane = threadIdx.x & 31;
  if (g >= E) return;
  int src = ei[g];
  int dst = ei[E + g];
  const float4 q = *(const float4*)(Q + (size_t)dst * 128 + lane * 4);
  const float4 k = *(const float4*)(Kf + (size_t)src * 128 + lane * 4);
  float part = q.x * k.x + q.y * k.y + q.z * k.z + q.w * k.w;
  part += __shfl_xor(part, 1);
  part += __shfl_xor(part, 2);
  part += __shfl_xor(part, 4);
  if ((lane & 7) == 0) {
    int h = lane >> 3;
    float lg = part * 0.17677669529663687f;  // 1/sqrt(32)
    LG[(size_t)g * 4 + h] = lg;
    atomicMax(&Mx[(size_t)dst * 4 + h], fkey(lg));
  }
}

__global__ void edge_expsum1(const int* __restrict__ ei, float* __restrict__ LG,
                             const unsigned* __restrict__ Mx, float* __restrict__ D, int E) {
  int t = blockIdx.x * blockDim.x + threadIdx.x;
  if (t >= E * 4) return;
  int e = t >> 2, h = t & 3;
  int dst = ei[E + e];
  float m = fdecode(Mx[(size_t)dst * 4 + h]);
  float p = __expf(LG[t] - m);
  LG[t] = p;
  atomicAdd(&D[(size_t)dst * 4 + h], p);
}

__global__ void edge_aggr1(const int* __restrict__ ei, const float* __restrict__ LG,
                           const float* __restrict__ D, const float* __restrict__ V,
                           float* __restrict__ H, int E) {
  int g = (blockIdx.x * blockDim.x + threadIdx.x) >> 5;
  int lane = threadIdx.x & 31;
  if (g >= E) return;
  int src = ei[g];
  int dst = ei[E + g];
  int h = lane >> 3;
  float alpha = LG[(size_t)g * 4 + h] / D[(size_t)dst * 4 + h];
  const float4 v = *(const float4*)(V + (size_t)src * 128 + lane * 4);
  float* out = H + (size_t)dst * 128 + lane * 4;
  atomicAdd(out + 0, alpha * v.x);
  atomicAdd(out + 1, alpha * v.y);
  atomicAdd(out + 2, alpha * v.z);
  atomicAdd(out + 3, alpha * v.w);
}

// ---------------- conv2 edge kernels (1 head x 32 dims) ----------------
__global__ void edge_logits2(const int* __restrict__ ei, const float* __restrict__ Q,
                             const float* __restrict__ Kf, float* __restrict__ LG,
                             unsigned* __restrict__ Mx, int E) {
  int g = (blockIdx.x * blockDim.x + threadIdx.x) >> 5;
  int lane = threadIdx.x & 31;
  if (g >= E) return;
  int src = ei[g];
  int dst = ei[E + g];
  float part = Q[(size_t)dst * 32 + lane] * Kf[(size_t)src * 32 + lane];
  part += __shfl_xor(part, 1);
  part += __shfl_xor(part, 2);
  part += __shfl_xor(part, 4);
  part += __shfl_xor(part, 8);
  part += __shfl_xor(part, 16);
  if (lane == 0) {
    float lg = part * 0.17677669529663687f;
    LG[g] = lg;
    atomicMax(&Mx[dst], fkey(lg));
  }
}

__global__ void edge_expsum2(const int* __restrict__ ei, float* __restrict__ LG,
                             const unsigned* __restrict__ Mx, float* __restrict__ D, int E) {
  int e = blockIdx.x * blockDim.x + threadIdx.x;
  if (e >= E) return;
  int dst = ei[E + e];
  float m = fdecode(Mx[dst]);
  float p = __expf(LG[e] - m);
  LG[e] = p;
  atomicAdd(&D[dst], p);
}

__global__ void edge_aggr2(const int* __restrict__ ei, const float* __restrict__ LG,
                           const float* __restrict__ D, const float* __restrict__ V,
                           float* __restrict__ H, int E) {
  int g = (blockIdx.x * blockDim.x + threadIdx.x) >> 5;
  int lane = threadIdx.x & 31;
  if (g >= E) return;
  int src = ei[g];
  int dst = ei[E + g];
  float alpha = LG[g] / D[dst];
  float v = V[(size_t)src * 32 + lane];
  atomicAdd(&H[(size_t)dst * 32 + lane], alpha * v);
}

// ---------------- misc ----------------
__global__ void relu_kernel(float* __restrict__ H, int n) {
  int i = blockIdx.x * blockDim.x + threadIdx.x;
  if (i < n) H[i] = fmaxf(H[i], 0.f);
}

__global__ void mean_reduce(const float* __restrict__ H2, float* __restrict__ ACC, int total) {
  __shared__ float s[256];
  float acc = 0.f;
  int stride = gridDim.x * blockDim.x;  // multiple of 32
  for (int i = blockIdx.x * blockDim.x + threadIdx.x; i < total; i += stride)
    acc += fmaxf(H2[i], 0.f);  // relu fused here
  s[threadIdx.x] = acc;
  __syncthreads();
  for (int off = 128; off >= 32; off >>= 1) {
    if (threadIdx.x < off) s[threadIdx.x] += s[threadIdx.x + off];
    __syncthreads();
  }
  if (threadIdx.x < 32) atomicAdd(&ACC[threadIdx.x], s[threadIdx.x]);
}

__global__ void final_out(const float* __restrict__ ACC, const float* __restrict__ Wo,
                          const float* __restrict__ bo, float* __restrict__ out, float invN) {
  int lane = threadIdx.x;  // 64 threads, one wave
  float v = 0.f;
  if (lane < 32) v = ACC[lane] * invN * Wo[lane];
  v += __shfl_xor(v, 1);
  v += __shfl_xor(v, 2);
  v += __shfl_xor(v, 4);
  v += __shfl_xor(v, 8);
  v += __shfl_xor(v, 16);
  v += __shfl_xor(v, 32);
  if (lane == 0) out[0] = v + bo[0];
}

extern "C" void kernel_launch(void* const* d_in, const int* in_sizes, int n_in,
                              void* d_out, int out_size, void* d_ws, size_t ws_size,
                              hipStream_t stream) {
  const float* x   = (const float*)d_in[0];
  const int*   ei  = (const int*)d_in[1];  // [2, E]: row 0 = src, row 1 = dst
  const float* Wq1 = (const float*)d_in[2];  const float* bq1 = (const float*)d_in[3];
  const float* Wk1 = (const float*)d_in[4];  const float* bk1 = (const float*)d_in[5];
  const float* Wv1 = (const float*)d_in[6];  const float* bv1 = (const float*)d_in[7];
  const float* Ws1 = (const float*)d_in[8];  const float* bs1 = (const float*)d_in[9];
  const float* Wq2 = (const float*)d_in[10]; const float* bq2 = (const float*)d_in[11];
  const float* Wk2 = (const float*)d_in[12]; const float* bk2 = (const float*)d_in[13];
  const float* Wv2 = (const float*)d_in[14]; const float* bv2 = (const float*)d_in[15];
  const float* Ws2 = (const float*)d_in[16]; const float* bs2 = (const float*)d_in[17];
  const float* Wo  = (const float*)d_in[18]; const float* bo  = (const float*)d_in[19];

  char* ws = (char*)d_ws;
  const int N = N_NODES, E = N_EDGES;

  // conv1 region (peak ~117 MB)
  float*    Q1  = (float*)(ws + 0);            // N*128
  float*    K1  = (float*)(ws + 25600000);     // N*128
  float*    V1  = (float*)(ws + 51200000);     // N*128
  float*    H1  = (float*)(ws + 76800000);     // N*128 (conv1 out; relu'd in place)
  float*    LG1 = (float*)(ws + 102400000);    // E*4 (logits, then p)
  unsigned* M1  = (unsigned*)(ws + 115200000); // N*4
  float*    D1  = (float*)(ws + 116000000);    // N*4
  // conv2 region — overlays conv1's dead Q1/K1/V1 space
  float*    Q2  = (float*)(ws + 0);            // N*32
  float*    K2  = (float*)(ws + 6400000);      // N*32
  float*    V2  = (float*)(ws + 12800000);     // N*32
  float*    LG2 = (float*)(ws + 19200000);     // E
  unsigned* M2  = (unsigned*)(ws + 25600000);  // N
  float*    D2  = (float*)(ws + 25800000);     // N
  float*    ACC = (float*)(ws + 26000000);     // 32
  float*    H2  = (float*)(ws + 51200000);     // N*32 (overlays V1)

  float* out = (float*)d_out;

  // zero accumulators (graph-capture safe)
  hipMemsetAsync(M1, 0, (size_t)N * 4 * sizeof(unsigned), stream);
  hipMemsetAsync(D1, 0, (size_t)N * 4 * sizeof(float), stream);
  hipMemsetAsync(M2, 0, (size_t)N * sizeof(unsigned), stream);
  hipMemsetAsync(D2, 0, (size_t)N * sizeof(float), stream);
  hipMemsetAsync(ACC, 0, 32 * sizeof(float), stream);

  dim3 blk(256);

  // ---- conv1 linears: [N,128] @ [128,128] + b ----
  dim3 g1((N + 127) / 128, 2);  // BN=64, Nout=128
  linear_kernel<4><<<g1, blk, 0, stream>>>(x, Wq1, bq1, Q1, N, 128, 128);
  linear_kernel<4><<<g1, blk, 0, stream>>>(x, Wk1, bk1, K1, N, 128, 128);
  linear_kernel<4><<<g1, blk, 0, stream>>>(x, Wv1, bv1, V1, N, 128, 128);
  linear_kernel<4><<<g1, blk, 0, stream>>>(x, Ws1, bs1, H1, N, 128, 128);

  // ---- conv1 edge phase ----
  dim3 ge((E * 32 + 255) / 256);  // 32 lanes/edge
  edge_logits1<<<ge, blk, 0, stream>>>(ei, Q1, K1, LG1, M1, E);
  edge_expsum1<<<dim3((E * 4 + 255) / 256), blk, 0, stream>>>(ei, LG1, M1, D1, E);
  edge_aggr1<<<ge, blk, 0, stream>>>(ei, LG1, D1, V1, H1, E);

  // relu(H1) in place
  relu_kernel<<<dim3((N * 128 + 255) / 256), blk, 0, stream>>>(H1, N * 128);

  // ---- conv2 linears: [N,128] @ [128,32] + b ----
  dim3 g2((N + 127) / 128, 1);  // BN=32
  linear_kernel<2><<<g2, blk, 0, stream>>>(H1, Wq2, bq2, Q2, N, 128, 32);
  linear_kernel<2><<<g2, blk, 0, stream>>>(H1, Wk2, bk2, K2, N, 128, 32);
  linear_kernel<2><<<g2, blk, 0, stream>>>(H1, Wv2, bv2, V2, N, 128, 32);
  linear_kernel<2><<<g2, blk, 0, stream>>>(H1, Ws2, bs2, H2, N, 128, 32);

  // ---- conv2 edge phase ----
  edge_logits2<<<ge, blk, 0, stream>>>(ei, Q2, K2, LG2, M2, E);
  edge_expsum2<<<dim3((E + 255) / 256), blk, 0, stream>>>(ei, LG2, M2, D2, E);
  edge_aggr2<<<ge, blk, 0, stream>>>(ei, LG2, D2, V2, H2, E);

  // ---- relu + mean + final linear ----
  mean_reduce<<<dim3(1024), blk, 0, stream>>>(H2, ACC, N * 32);
  final_out<<<dim3(1), dim3(64), 0, stream>>>(ACC, Wo, bo, out, 1.0f / (float)N);
}

// Round 2
// 806.772 us; speedup vs baseline: 2.6268x; 2.6268x over previous
//
#include <hip/hip_runtime.h>
#include <math.h>

#define N_NODES 50000
#define N_EDGES 800000

// ---------------- GEMM: C[M,N] = A[M,K] @ W[K,N] + bias ----------------
// BM=128, BK=16, BN=TN*16, block=256 threads, micro-tile 8 x TN per thread.
template <int TN>
__global__ void linear_kernel(const float* __restrict__ A, const float* __restrict__ W,
                              const float* __restrict__ bias, float* __restrict__ C,
                              int M, int K, int N) {
  constexpr int BM = 128, BK = 16;
  constexpr int BN = TN * 16;
  __shared__ float As[BK][BM + 4];
  __shared__ float Bs[BK][BN + 4];
  const int bm = blockIdx.x * BM;
  const int bn = blockIdx.y * BN;
  const int tid = threadIdx.x;       // 256 threads
  const int tx = tid % 16;           // 16 col-groups
  const int ty = tid / 16;           // 16 row-groups (8 rows each)

  float acc[8][TN];
#pragma unroll
  for (int i = 0; i < 8; ++i)
#pragma unroll
    for (int j = 0; j < TN; ++j) acc[i][j] = 0.f;

  for (int k0 = 0; k0 < K; k0 += BK) {
#pragma unroll
    for (int p = 0; p < 8; ++p) {
      int ml = tid / 16 + p * 16;
      int kk = tid % 16;
      int m = bm + ml;
      As[kk][ml] = (m < M) ? A[(size_t)m * K + k0 + kk] : 0.f;
    }
#pragma unroll
    for (int p = 0; p < (BK * BN) / 256; ++p) {
      int idx = tid + p * 256;
      int kk = idx / BN;
      int nl = idx % BN;
      int n = bn + nl;
      Bs[kk][nl] = (n < N) ? W[(size_t)(k0 + kk) * N + n] : 0.f;
    }
    __syncthreads();
#pragma unroll
    for (int kk = 0; kk < BK; ++kk) {
      float a[8], bb[TN];
#pragma unroll
      for (int i = 0; i < 8; ++i) a[i] = As[kk][ty * 8 + i];
#pragma unroll
      for (int j = 0; j < TN; ++j) bb[j] = Bs[kk][tx * TN + j];
#pragma unroll
      for (int i = 0; i < 8; ++i)
#pragma unroll
        for (int j = 0; j < TN; ++j) acc[i][j] += a[i] * bb[j];
    }
    __syncthreads();
  }
#pragma unroll
  for (int i = 0; i < 8; ++i) {
    int m = bm + ty * 8 + i;
    if (m >= M) continue;
#pragma unroll
    for (int j = 0; j < TN; ++j) {
      int n = bn + tx * TN + j;
      if (n < N) C[(size_t)m * N + n] = acc[i][j] + bias[n];
    }
  }
}

// ---------------- CSR build ----------------
__global__ void deg_count(const int* __restrict__ ei, int* __restrict__ deg, int E) {
  int e = blockIdx.x * blockDim.x + threadIdx.x;
  if (e < E) atomicAdd(&deg[ei[E + e]], 1);
}

// single-block exclusive scan over n=50000: writes rowptr[0..n] and cur[0..n-1]
__global__ void scan_kernel(const int* __restrict__ deg, int* __restrict__ rowptr,
                            int* __restrict__ cur, int n) {
  __shared__ int s[1024];
  const int t = threadIdx.x;         // 1024 threads
  const int C = (n + 1023) / 1024;
  const int base = t * C;
  int sum = 0;
  for (int i = 0; i < C; ++i) {
    int idx = base + i;
    if (idx < n) sum += deg[idx];
  }
  s[t] = sum;
  __syncthreads();
  for (int off = 1; off < 1024; off <<= 1) {
    int v = (t >= off) ? s[t - off] : 0;
    __syncthreads();
    s[t] += v;
    __syncthreads();
  }
  int run = (t == 0) ? 0 : s[t - 1];
  for (int i = 0; i < C; ++i) {
    int idx = base + i;
    if (idx < n) {
      rowptr[idx] = run;
      cur[idx] = run;
      run += deg[idx];
    }
  }
  if (t == 1023) rowptr[n] = s[1023];
}

__global__ void scatter_edges(const int* __restrict__ ei, int* __restrict__ cur,
                              int* __restrict__ esrc, int E) {
  int e = blockIdx.x * blockDim.x + threadIdx.x;
  if (e >= E) return;
  int src = ei[e];
  int dst = ei[E + e];
  int pos = atomicAdd(&cur[dst], 1);
  esrc[pos] = src;
}

// ---------------- fused online-softmax aggregation ----------------
// conv1: 4 heads x 32 dims = 128. One wave (64 lanes) per dst node; each lane
// owns 2 dims (float2). 16 lanes per head -> shfl_xor 1,2,4,8 reduces per head.
// Epilogue: H = relu(skip + aggr/l)  (skip pre-stored in H by linear_kernel).
__global__ void node_attn1(const int* __restrict__ rowptr, const int* __restrict__ esrc,
                           const float* __restrict__ Q, const float* __restrict__ K,
                           const float* __restrict__ V, float* __restrict__ H, int n) {
  int node = (blockIdx.x * blockDim.x + threadIdx.x) >> 6;
  int lane = threadIdx.x & 63;
  if (node >= n) return;
  const int r0 = rowptr[node], r1 = rowptr[node + 1];
  const float2 q = *(const float2*)(Q + (size_t)node * 128 + lane * 2);
  float m = -INFINITY, l = 0.f;
  float2 acc = {0.f, 0.f};
  for (int j = r0; j < r1; ++j) {
    int src = esrc[j];
    const float2 k = *(const float2*)(K + (size_t)src * 128 + lane * 2);
    const float2 v = *(const float2*)(V + (size_t)src * 128 + lane * 2);
    float part = q.x * k.x + q.y * k.y;
    part += __shfl_xor(part, 1);
    part += __shfl_xor(part, 2);
    part += __shfl_xor(part, 4);
    part += __shfl_xor(part, 8);
    float lg = part * 0.17677669529663687f;  // 1/sqrt(32)
    float mnew = fmaxf(m, lg);
    float scale = __expf(m - mnew);          // first iter: exp(-inf)=0
    float p = __expf(lg - mnew);
    l = l * scale + p;
    acc.x = acc.x * scale + p * v.x;
    acc.y = acc.y * scale + p * v.y;
    m = mnew;
  }
  float inv = (l > 0.f) ? 1.f / l : 0.f;
  float* h = H + (size_t)node * 128 + lane * 2;
  float2 skip = *(float2*)h;
  float2 o;
  o.x = fmaxf(skip.x + acc.x * inv, 0.f);    // fused relu
  o.y = fmaxf(skip.y + acc.y * inv, 0.f);
  *(float2*)h = o;
}

// conv2: 1 head x 32 dims. 32 lanes per node (2 nodes per wave).
// Epilogue: H += aggr/l   (relu applied later in mean_reduce).
__global__ void node_attn2(const int* __restrict__ rowptr, const int* __restrict__ esrc,
                           const float* __restrict__ Q, const float* __restrict__ K,
                           const float* __restrict__ V, float* __restrict__ H, int n) {
  int t = blockIdx.x * blockDim.x + threadIdx.x;
  int node = t >> 5;
  int lane = threadIdx.x & 31;
  if (node >= n) return;
  const int r0 = rowptr[node], r1 = rowptr[node + 1];
  const float q = Q[(size_t)node * 32 + lane];
  float m = -INFINITY, l = 0.f, acc = 0.f;
  for (int j = r0; j < r1; ++j) {
    int src = esrc[j];
    float k = K[(size_t)src * 32 + lane];
    float v = V[(size_t)src * 32 + lane];
    float part = q * k;
    part += __shfl_xor(part, 1);
    part += __shfl_xor(part, 2);
    part += __shfl_xor(part, 4);
    part += __shfl_xor(part, 8);
    part += __shfl_xor(part, 16);            // stays within each 32-lane half
    float lg = part * 0.17677669529663687f;
    float mnew = fmaxf(m, lg);
    float scale = __expf(m - mnew);
    float p = __expf(lg - mnew);
    l = l * scale + p;
    acc = acc * scale + p * v;
    m = mnew;
  }
  float inv = (l > 0.f) ? 1.f / l : 0.f;
  float* h = H + (size_t)node * 32 + lane;
  *h = *h + acc * inv;
}

// ---------------- epilogue ----------------
__global__ void mean_reduce(const float* __restrict__ H2, float* __restrict__ ACC, int total) {
  __shared__ float s[256];
  float acc = 0.f;
  int stride = gridDim.x * blockDim.x;
  for (int i = blockIdx.x * blockDim.x + threadIdx.x; i < total; i += stride)
    acc += fmaxf(H2[i], 0.f);  // relu fused
  s[threadIdx.x] = acc;
  __syncthreads();
  for (int off = 128; off >= 32; off >>= 1) {
    if (threadIdx.x < off) s[threadIdx.x] += s[threadIdx.x + off];
    __syncthreads();
  }
  if (threadIdx.x < 32) atomicAdd(&ACC[threadIdx.x], s[threadIdx.x]);
}

__global__ void final_out(const float* __restrict__ ACC, const float* __restrict__ Wo,
                          const float* __restrict__ bo, float* __restrict__ out, float invN) {
  int lane = threadIdx.x;  // 64 threads, one wave
  float v = 0.f;
  if (lane < 32) v = ACC[lane] * invN * Wo[lane];
  v += __shfl_xor(v, 1);
  v += __shfl_xor(v, 2);
  v += __shfl_xor(v, 4);
  v += __shfl_xor(v, 8);
  v += __shfl_xor(v, 16);
  v += __shfl_xor(v, 32);
  if (lane == 0) out[0] = v + bo[0];
}

extern "C" void kernel_launch(void* const* d_in, const int* in_sizes, int n_in,
                              void* d_out, int out_size, void* d_ws, size_t ws_size,
                              hipStream_t stream) {
  const float* x   = (const float*)d_in[0];
  const int*   ei  = (const int*)d_in[1];  // [2, E]: row 0 = src, row 1 = dst
  const float* Wq1 = (const float*)d_in[2];  const float* bq1 = (const float*)d_in[3];
  const float* Wk1 = (const float*)d_in[4];  const float* bk1 = (const float*)d_in[5];
  const float* Wv1 = (const float*)d_in[6];  const float* bv1 = (const float*)d_in[7];
  const float* Ws1 = (const float*)d_in[8];  const float* bs1 = (const float*)d_in[9];
  const float* Wq2 = (const float*)d_in[10]; const float* bq2 = (const float*)d_in[11];
  const float* Wk2 = (const float*)d_in[12]; const float* bk2 = (const float*)d_in[13];
  const float* Wv2 = (const float*)d_in[14]; const float* bv2 = (const float*)d_in[15];
  const float* Ws2 = (const float*)d_in[16]; const float* bs2 = (const float*)d_in[17];
  const float* Wo  = (const float*)d_in[18]; const float* bo  = (const float*)d_in[19];

  char* ws = (char*)d_ws;
  const int N = N_NODES, E = N_EDGES;

  // conv1 buffers
  float* Q1 = (float*)(ws + 0);          // N*128
  float* K1 = (float*)(ws + 25600000);   // N*128
  float* V1 = (float*)(ws + 51200000);   // N*128
  float* H1 = (float*)(ws + 76800000);   // N*128 (skip -> conv1 out, relu'd)
  // CSR (shared by both convs)
  int* rowptr = (int*)(ws + 102400000);  // N+1
  int* cur    = (int*)(ws + 102700000);  // N
  int* esrc   = (int*)(ws + 103000000);  // E
  int* deg    = (int*)(ws + 106300000);  // N
  float* ACC  = (float*)(ws + 106600000);// 32
  // conv2 buffers — overlay dead Q1/K1/V1 regions (H1 stays live as input)
  float* Q2 = (float*)(ws + 0);          // N*32
  float* K2 = (float*)(ws + 6400000);    // N*32
  float* V2 = (float*)(ws + 12800000);   // N*32
  float* H2 = (float*)(ws + 19200000);   // N*32

  float* out = (float*)d_out;

  hipMemsetAsync(deg, 0, (size_t)N * sizeof(int), stream);
  hipMemsetAsync(ACC, 0, 32 * sizeof(float), stream);

  dim3 blk(256);

  // ---- CSR build (once; reused by both convs) ----
  deg_count<<<dim3((E + 255) / 256), blk, 0, stream>>>(ei, deg, E);
  scan_kernel<<<dim3(1), dim3(1024), 0, stream>>>(deg, rowptr, cur, N);
  scatter_edges<<<dim3((E + 255) / 256), blk, 0, stream>>>(ei, cur, esrc, E);

  // ---- conv1 linears: [N,128] @ [128,128] + b ----
  dim3 g1((N + 127) / 128, 2);  // BN=64
  linear_kernel<4><<<g1, blk, 0, stream>>>(x, Wq1, bq1, Q1, N, 128, 128);
  linear_kernel<4><<<g1, blk, 0, stream>>>(x, Wk1, bk1, K1, N, 128, 128);
  linear_kernel<4><<<g1, blk, 0, stream>>>(x, Wv1, bv1, V1, N, 128, 128);
  linear_kernel<4><<<g1, blk, 0, stream>>>(x, Ws1, bs1, H1, N, 128, 128);

  // ---- conv1 fused attention + aggregation + skip + relu ----
  node_attn1<<<dim3((N * 64 + 255) / 256), blk, 0, stream>>>(rowptr, esrc, Q1, K1, V1, H1, N);

  // ---- conv2 linears: [N,128] @ [128,32] + b ----
  dim3 g2((N + 127) / 128, 1);  // BN=32
  linear_kernel<2><<<g2, blk, 0, stream>>>(H1, Wq2, bq2, Q2, N, 128, 32);
  linear_kernel<2><<<g2, blk, 0, stream>>>(H1, Wk2, bk2, K2, N, 128, 32);
  linear_kernel<2><<<g2, blk, 0, stream>>>(H1, Wv2, bv2, V2, N, 128, 32);
  linear_kernel<2><<<g2, blk, 0, stream>>>(H1, Ws2, bs2, H2, N, 128, 32);

  // ---- conv2 fused attention + aggregation ----
  node_attn2<<<dim3((N * 32 + 255) / 256), blk, 0, stream>>>(rowptr, esrc, Q2, K2, V2, H2, N);

  // ---- relu + mean + final linear ----
  mean_reduce<<<dim3(1024), blk, 0, stream>>>(H2, ACC, N * 32);
  final_out<<<dim3(1), dim3(64), 0, stream>>>(ACC, Wo, bo, out, 1.0f / (float)N);
}

// Round 3
// 660.688 us; speedup vs baseline: 3.2076x; 1.2211x over previous
//
#include <hip/hip_runtime.h>
#include <math.h>

#define N_NODES 50000
#define N_EDGES 800000

// ---------------- bf16 helpers ----------------
__device__ inline unsigned short f2bf(float v) {
  unsigned u = __float_as_uint(v);
  u += 0x7FFFu + ((u >> 16) & 1u);  // round-to-nearest-even
  return (unsigned short)(u >> 16);
}
__device__ inline float bf2f(unsigned short b) {
  return __uint_as_float(((unsigned)b) << 16);
}

// ---------------- fused GEMM: C[M, 4*seg] = A[M,K] @ Wcat[K, 4*seg] + bcat ----------------
// BM=128, BN=128, BK=16, 256 threads, 8x8 micro-tile.
// Output column segment mi = col >> SEG_SHIFT routes to out0..out3.
// out1/out2 (K,V) are written as bf16; out0/out3 (Q, skip) as fp32.
template <int SEG_SHIFT>
__global__ __launch_bounds__(256) void fused_linear(
    const float* __restrict__ A, const float* __restrict__ Wcat, const float* __restrict__ bcat,
    float* __restrict__ out0, unsigned short* __restrict__ out1,
    unsigned short* __restrict__ out2, float* __restrict__ out3,
    int M, int K, int Ncat) {
  constexpr int BM = 128, BN = 128, BK = 16;
  constexpr int SEG = 1 << SEG_SHIFT;
  __shared__ float As[BK][BM + 4];
  __shared__ float Bs[BK][BN + 4];
  const int bm = blockIdx.x * BM;
  const int bn = blockIdx.y * BN;
  const int tid = threadIdx.x;
  const int tx = tid % 16;   // col group (8 cols)
  const int ty = tid / 16;   // row group (8 rows)

  float acc[8][8];
#pragma unroll
  for (int i = 0; i < 8; ++i)
#pragma unroll
    for (int j = 0; j < 8; ++j) acc[i][j] = 0.f;

  for (int k0 = 0; k0 < K; k0 += BK) {
    // A tile: 128 rows x 16 k -> 512 float4s, 2 per thread
#pragma unroll
    for (int p = 0; p < 2; ++p) {
      int f = tid + p * 256;
      int m = f >> 2;          // 0..127
      int g = f & 3;           // k-group of 4
      float4 a4 = {0.f, 0.f, 0.f, 0.f};
      if (bm + m < M) a4 = *(const float4*)(A + (size_t)(bm + m) * K + k0 + g * 4);
      As[g * 4 + 0][m] = a4.x;
      As[g * 4 + 1][m] = a4.y;
      As[g * 4 + 2][m] = a4.z;
      As[g * 4 + 3][m] = a4.w;
    }
    // B tile: 16 k x 128 cols -> 512 float4s, 2 per thread
#pragma unroll
    for (int p = 0; p < 2; ++p) {
      int f = tid + p * 256;
      int kk = f >> 5;         // 0..15
      int cg = f & 31;         // col group of 4
      float4 b4 = *(const float4*)(Wcat + (size_t)(k0 + kk) * Ncat + bn + cg * 4);
      *(float4*)&Bs[kk][cg * 4] = b4;
    }
    __syncthreads();
#pragma unroll
    for (int kk = 0; kk < BK; ++kk) {
      float a[8], b[8];
      *(float4*)&a[0] = *(float4*)&As[kk][ty * 8];
      *(float4*)&a[4] = *(float4*)&As[kk][ty * 8 + 4];
      *(float4*)&b[0] = *(float4*)&Bs[kk][tx * 8];
      *(float4*)&b[4] = *(float4*)&Bs[kk][tx * 8 + 4];
#pragma unroll
      for (int i = 0; i < 8; ++i)
#pragma unroll
        for (int j = 0; j < 8; ++j) acc[i][j] += a[i] * b[j];
    }
    __syncthreads();
  }

  // epilogue: 8 cols of this thread all live in one segment (8 | SEG)
  const int c0 = bn + tx * 8;          // global col of j=0
  const int mi = c0 >> SEG_SHIFT;      // which output matrix
  const int lc0 = c0 & (SEG - 1);      // local col
  float bias[8];
#pragma unroll
  for (int j = 0; j < 8; ++j) bias[j] = bcat[c0 + j];
#pragma unroll
  for (int i = 0; i < 8; ++i) {
    int m = bm + ty * 8 + i;
    if (m >= M) continue;
    if (mi == 0) {
      float* o = out0 + (size_t)m * SEG + lc0;
#pragma unroll
      for (int j = 0; j < 8; ++j) o[j] = acc[i][j] + bias[j];
    } else if (mi == 1) {
      unsigned short* o = out1 + (size_t)m * SEG + lc0;
#pragma unroll
      for (int j = 0; j < 8; ++j) o[j] = f2bf(acc[i][j] + bias[j]);
    } else if (mi == 2) {
      unsigned short* o = out2 + (size_t)m * SEG + lc0;
#pragma unroll
      for (int j = 0; j < 8; ++j) o[j] = f2bf(acc[i][j] + bias[j]);
    } else {
      float* o = out3 + (size_t)m * SEG + lc0;
#pragma unroll
      for (int j = 0; j < 8; ++j) o[j] = acc[i][j] + bias[j];
    }
  }
}

// ---------------- weight concat ----------------
__global__ void concat_w(const float* __restrict__ W0, const float* __restrict__ W1,
                         const float* __restrict__ W2, const float* __restrict__ W3,
                         const float* __restrict__ b0, const float* __restrict__ b1,
                         const float* __restrict__ b2, const float* __restrict__ b3,
                         float* __restrict__ Wcat, float* __restrict__ bcat,
                         int K, int segN) {
  int i = blockIdx.x * blockDim.x + threadIdx.x;
  int Ncat = 4 * segN;
  if (i < K * Ncat) {
    int r = i / Ncat, c = i % Ncat;
    int mi = c / segN, lc = c % segN;
    const float* W = (mi == 0) ? W0 : (mi == 1) ? W1 : (mi == 2) ? W2 : W3;
    Wcat[i] = W[(size_t)r * segN + lc];
  }
  if (i < Ncat) {
    int mi = i / segN, lc = i % segN;
    const float* b = (mi == 0) ? b0 : (mi == 1) ? b1 : (mi == 2) ? b2 : b3;
    bcat[i] = b[lc];
  }
}

// ---------------- CSR build ----------------
__global__ void deg_count(const int* __restrict__ ei, int* __restrict__ deg, int E) {
  int e = blockIdx.x * blockDim.x + threadIdx.x;
  if (e < E) atomicAdd(&deg[ei[E + e]], 1);
}

__global__ void scan_kernel(const int* __restrict__ deg, int* __restrict__ rowptr,
                            int* __restrict__ cur, int n) {
  __shared__ int s[1024];
  const int t = threadIdx.x;
  const int C = (n + 1023) / 1024;
  const int base = t * C;
  int sum = 0;
  for (int i = 0; i < C; ++i) {
    int idx = base + i;
    if (idx < n) sum += deg[idx];
  }
  s[t] = sum;
  __syncthreads();
  for (int off = 1; off < 1024; off <<= 1) {
    int v = (t >= off) ? s[t - off] : 0;
    __syncthreads();
    s[t] += v;
    __syncthreads();
  }
  int run = (t == 0) ? 0 : s[t - 1];
  for (int i = 0; i < C; ++i) {
    int idx = base + i;
    if (idx < n) {
      rowptr[idx] = run;
      cur[idx] = run;
      run += deg[idx];
    }
  }
  if (t == 1023) rowptr[n] = s[1023];
}

__global__ void scatter_edges(const int* __restrict__ ei, int* __restrict__ cur,
                              int* __restrict__ esrc, int E) {
  int e = blockIdx.x * blockDim.x + threadIdx.x;
  if (e >= E) return;
  int src = ei[e];
  int dst = ei[E + e];
  int pos = atomicAdd(&cur[dst], 1);
  esrc[pos] = src;
}

// ---------------- fused online-softmax aggregation ----------------
// conv1: 4 heads x 32 dims. One wave per node; lane owns 2 dims (bf16x2 = 4B gathers).
__global__ void node_attn1(const int* __restrict__ rowptr, const int* __restrict__ esrc,
                           const float* __restrict__ Q, const unsigned short* __restrict__ Kb,
                           const unsigned short* __restrict__ Vb, float* __restrict__ H, int n) {
  int node = (blockIdx.x * blockDim.x + threadIdx.x) >> 6;
  int lane = threadIdx.x & 63;
  if (node >= n) return;
  const int r0 = rowptr[node], r1 = rowptr[node + 1];
  const float2 q = *(const float2*)(Q + (size_t)node * 128 + lane * 2);
  float m = -INFINITY, l = 0.f;
  float2 acc = {0.f, 0.f};
  for (int j = r0; j < r1; ++j) {
    int src = esrc[j];
    unsigned ku = *(const unsigned*)(Kb + (size_t)src * 128 + lane * 2);
    unsigned vu = *(const unsigned*)(Vb + (size_t)src * 128 + lane * 2);
    float kx = __uint_as_float((ku & 0xFFFFu) << 16);
    float ky = __uint_as_float(ku & 0xFFFF0000u);
    float vx = __uint_as_float((vu & 0xFFFFu) << 16);
    float vy = __uint_as_float(vu & 0xFFFF0000u);
    float part = q.x * kx + q.y * ky;
    part += __shfl_xor(part, 1);
    part += __shfl_xor(part, 2);
    part += __shfl_xor(part, 4);
    part += __shfl_xor(part, 8);
    float lg = part * 0.17677669529663687f;  // 1/sqrt(32)
    float mnew = fmaxf(m, lg);
    float scale = __expf(m - mnew);
    float p = __expf(lg - mnew);
    l = l * scale + p;
    acc.x = acc.x * scale + p * vx;
    acc.y = acc.y * scale + p * vy;
    m = mnew;
  }
  float inv = (l > 0.f) ? 1.f / l : 0.f;
  float* h = H + (size_t)node * 128 + lane * 2;
  float2 skip = *(float2*)h;
  float2 o;
  o.x = fmaxf(skip.x + acc.x * inv, 0.f);    // fused relu
  o.y = fmaxf(skip.y + acc.y * inv, 0.f);
  *(float2*)h = o;
}

// conv2: 1 head x 32 dims. 32 lanes per node; bf16 scalar gathers (2B/lane).
__global__ void node_attn2(const int* __restrict__ rowptr, const int* __restrict__ esrc,
                           const float* __restrict__ Q, const unsigned short* __restrict__ Kb,
                           const unsigned short* __restrict__ Vb, float* __restrict__ H, int n) {
  int t = blockIdx.x * blockDim.x + threadIdx.x;
  int node = t >> 5;
  int lane = threadIdx.x & 31;
  if (node >= n) return;
  const int r0 = rowptr[node], r1 = rowptr[node + 1];
  const float q = Q[(size_t)node * 32 + lane];
  float m = -INFINITY, l = 0.f, acc = 0.f;
  for (int j = r0; j < r1; ++j) {
    int src = esrc[j];
    float k = bf2f(Kb[(size_t)src * 32 + lane]);
    float v = bf2f(Vb[(size_t)src * 32 + lane]);
    float part = q * k;
    part += __shfl_xor(part, 1);
    part += __shfl_xor(part, 2);
    part += __shfl_xor(part, 4);
    part += __shfl_xor(part, 8);
    part += __shfl_xor(part, 16);
    float lg = part * 0.17677669529663687f;
    float mnew = fmaxf(m, lg);
    float scale = __expf(m - mnew);
    float p = __expf(lg - mnew);
    l = l * scale + p;
    acc = acc * scale + p * v;
    m = mnew;
  }
  float inv = (l > 0.f) ? 1.f / l : 0.f;
  float* h = H + (size_t)node * 32 + lane;
  *h = *h + acc * inv;
}

// ---------------- epilogue ----------------
__global__ void mean_reduce(const float* __restrict__ H2, float* __restrict__ ACC, int total) {
  __shared__ float s[256];
  float acc = 0.f;
  int stride = gridDim.x * blockDim.x;
  for (int i = blockIdx.x * blockDim.x + threadIdx.x; i < total; i += stride)
    acc += fmaxf(H2[i], 0.f);  // relu fused
  s[threadIdx.x] = acc;
  __syncthreads();
  for (int off = 128; off >= 32; off >>= 1) {
    if (threadIdx.x < off) s[threadIdx.x] += s[threadIdx.x + off];
    __syncthreads();
  }
  if (threadIdx.x < 32) atomicAdd(&ACC[threadIdx.x], s[threadIdx.x]);
}

__global__ void final_out(const float* __restrict__ ACC, const float* __restrict__ Wo,
                          const float* __restrict__ bo, float* __restrict__ out, float invN) {
  int lane = threadIdx.x;
  float v = 0.f;
  if (lane < 32) v = ACC[lane] * invN * Wo[lane];
  v += __shfl_xor(v, 1);
  v += __shfl_xor(v, 2);
  v += __shfl_xor(v, 4);
  v += __shfl_xor(v, 8);
  v += __shfl_xor(v, 16);
  v += __shfl_xor(v, 32);
  if (lane == 0) out[0] = v + bo[0];
}

extern "C" void kernel_launch(void* const* d_in, const int* in_sizes, int n_in,
                              void* d_out, int out_size, void* d_ws, size_t ws_size,
                              hipStream_t stream) {
  const float* x   = (const float*)d_in[0];
  const int*   ei  = (const int*)d_in[1];  // [2, E]: row 0 = src, row 1 = dst
  const float* Wq1 = (const float*)d_in[2];  const float* bq1 = (const float*)d_in[3];
  const float* Wk1 = (const float*)d_in[4];  const float* bk1 = (const float*)d_in[5];
  const float* Wv1 = (const float*)d_in[6];  const float* bv1 = (const float*)d_in[7];
  const float* Ws1 = (const float*)d_in[8];  const float* bs1 = (const float*)d_in[9];
  const float* Wq2 = (const float*)d_in[10]; const float* bq2 = (const float*)d_in[11];
  const float* Wk2 = (const float*)d_in[12]; const float* bk2 = (const float*)d_in[13];
  const float* Wv2 = (const float*)d_in[14]; const float* bv2 = (const float*)d_in[15];
  const float* Ws2 = (const float*)d_in[16]; const float* bs2 = (const float*)d_in[17];
  const float* Wo  = (const float*)d_in[18]; const float* bo  = (const float*)d_in[19];

  char* ws = (char*)d_ws;
  const int N = N_NODES, E = N_EDGES;

  // conv1 buffers
  float*          Q1  = (float*)(ws + 0);           // N*128 fp32 (25.6 MB)
  float*          H1  = (float*)(ws + 25600000);    // N*128 fp32 (skip -> conv1 out)
  unsigned short* K1b = (unsigned short*)(ws + 51200000);  // N*128 bf16 (12.8 MB)
  unsigned short* V1b = (unsigned short*)(ws + 64000000);  // N*128 bf16
  // CSR
  int* rowptr = (int*)(ws + 76800000);
  int* cur    = (int*)(ws + 77100000);
  int* esrc   = (int*)(ws + 77400000);
  int* deg    = (int*)(ws + 80700000);
  float* ACC  = (float*)(ws + 81000000);
  // weights
  float* Wcat1 = (float*)(ws + 81100000);  // 128x512
  float* bcat1 = (float*)(ws + 81400000);  // 512
  float* Wcat2 = (float*)(ws + 81500000);  // 128x128
  float* bcat2 = (float*)(ws + 81600000);  // 128
  // conv2 buffers — overlay Q1 region (dead after node_attn1)
  float*          Q2  = (float*)(ws + 0);          // N*32 fp32
  float*          H2  = (float*)(ws + 6400000);    // N*32 fp32
  unsigned short* K2b = (unsigned short*)(ws + 12800000);  // N*32 bf16
  unsigned short* V2b = (unsigned short*)(ws + 16000000);  // N*32 bf16

  float* out = (float*)d_out;

  hipMemsetAsync(deg, 0, (size_t)N * sizeof(int), stream);
  hipMemsetAsync(ACC, 0, 32 * sizeof(float), stream);

  dim3 blk(256);

  // ---- CSR build ----
  deg_count<<<dim3((E + 255) / 256), blk, 0, stream>>>(ei, deg, E);
  scan_kernel<<<dim3(1), dim3(1024), 0, stream>>>(deg, rowptr, cur, N);
  scatter_edges<<<dim3((E + 255) / 256), blk, 0, stream>>>(ei, cur, esrc, E);

  // ---- weight concat ----
  concat_w<<<dim3((128 * 512 + 255) / 256), blk, 0, stream>>>(
      Wq1, Wk1, Wv1, Ws1, bq1, bk1, bv1, bs1, Wcat1, bcat1, 128, 128);
  concat_w<<<dim3((128 * 128 + 255) / 256), blk, 0, stream>>>(
      Wq2, Wk2, Wv2, Ws2, bq2, bk2, bv2, bs2, Wcat2, bcat2, 128, 32);

  // ---- conv1 fused linears: [N,128] @ [128,512] ----
  fused_linear<7><<<dim3((N + 127) / 128, 4), blk, 0, stream>>>(
      x, Wcat1, bcat1, Q1, K1b, V1b, H1, N, 128, 512);

  // ---- conv1 fused attention + skip + relu ----
  node_attn1<<<dim3((N * 64 + 255) / 256), blk, 0, stream>>>(rowptr, esrc, Q1, K1b, V1b, H1, N);

  // ---- conv2 fused linears: [N,128] @ [128,128] ----
  fused_linear<5><<<dim3((N + 127) / 128, 1), blk, 0, stream>>>(
      H1, Wcat2, bcat2, Q2, K2b, V2b, H2, N, 128, 128);

  // ---- conv2 fused attention ----
  node_attn2<<<dim3((N * 32 + 255) / 256), blk, 0, stream>>>(rowptr, esrc, Q2, K2b, V2b, H2, N);

  // ---- relu + mean + final linear ----
  mean_reduce<<<dim3(1024), blk, 0, stream>>>(H2, ACC, N * 32);
  final_out<<<dim3(1), dim3(64), 0, stream>>>(ACC, Wo, bo, out, 1.0f / (float)N);
}

// Round 4
// 570.018 us; speedup vs baseline: 3.7178x; 1.1591x over previous
//
#include <hip/hip_runtime.h>
#include <math.h>

#define N_NODES 50000
#define N_EDGES 800000

typedef short short8 __attribute__((ext_vector_type(8)));
typedef float f32x4 __attribute__((ext_vector_type(4)));

// ---------------- bf16 helpers ----------------
__device__ inline unsigned short f2bf(float v) {
  unsigned u = __float_as_uint(v);
  u += 0x7FFFu + ((u >> 16) & 1u);  // round-to-nearest-even
  return (unsigned short)(u >> 16);
}
__device__ inline float bf2f(unsigned short b) {
  return __uint_as_float(((unsigned)b) << 16);
}

// ---------------- cast x -> bf16 ----------------
__global__ void cast_bf16(const float* __restrict__ in, unsigned short* __restrict__ out, int n4) {
  int i = blockIdx.x * blockDim.x + threadIdx.x;
  if (i >= n4) return;
  float4 v = ((const float4*)in)[i];
  ushort4 o;
  o.x = f2bf(v.x); o.y = f2bf(v.y); o.z = f2bf(v.z); o.w = f2bf(v.w);
  ((ushort4*)out)[i] = o;
}

// ---------------- weight concat + transpose + bf16 ----------------
// Wt[c][k] = W_{c/segN}[k][c%segN], bf16. bcat fp32.
__global__ void concat_wt(const float* __restrict__ W0, const float* __restrict__ W1,
                          const float* __restrict__ W2, const float* __restrict__ W3,
                          const float* __restrict__ b0, const float* __restrict__ b1,
                          const float* __restrict__ b2, const float* __restrict__ b3,
                          unsigned short* __restrict__ Wt, float* __restrict__ bcat,
                          int K, int segN) {
  int i = blockIdx.x * blockDim.x + threadIdx.x;
  int Ncat = 4 * segN;
  if (i < Ncat * K) {
    int c = i / K, k = i % K;
    int mi = c / segN, lc = c % segN;
    const float* W = (mi == 0) ? W0 : (mi == 1) ? W1 : (mi == 2) ? W2 : W3;
    Wt[i] = f2bf(W[(size_t)k * segN + lc]);
  }
  if (i < Ncat) {
    int mi = i / segN, lc = i % segN;
    const float* b = (mi == 0) ? b0 : (mi == 1) ? b1 : (mi == 2) ? b2 : b3;
    bcat[i] = b[lc];
  }
}

// ---------------- MFMA GEMM: [M,128] @ [128, 4*seg] with routed epilogue ----------------
// BM=128, BN=128, 256 threads = 4 waves, each wave a 64x64 subtile (4x4 of 16x16).
// K=128 staged in two 64-chunks. A, Wt in bf16; Wt is [Ncat][128] (pre-transposed).
// MODE 0 (conv1): blockIdx.y = segment (0=Q fp32, 1=K->KV, 2=V->KV, 3=H fp32), SEG=128.
// MODE 1 (conv2): single col-block; segment = col>>5 (0=Q,1=K,2=V,3=H), SEG=32.
// KV interleave conv1: K[m][c] -> KV[m*256 + (c>>1)*4 + (c&1)], V -> +2.
// KV interleave conv2: K[m][c] -> KV[m*64 + c*2], V -> +1.
template <int MODE>
__global__ __launch_bounds__(256) void mfma_linear(
    const unsigned short* __restrict__ Ab, const unsigned short* __restrict__ Wt,
    const float* __restrict__ bcat, float* __restrict__ Qout,
    unsigned short* __restrict__ KV, float* __restrict__ Hout, int M) {
  __shared__ __align__(16) unsigned short As[128][72];
  __shared__ __align__(16) unsigned short Bs[128][72];
  const int bm = blockIdx.x * 128;
  const int bn = blockIdx.y * 128;
  const int tid = threadIdx.x;
  const int wave = tid >> 6;
  const int lane = tid & 63;
  const int wx = wave & 1;     // col half
  const int wy = wave >> 1;    // row half
  const int lr = lane & 15;
  const int q = lane >> 4;

  f32x4 acc[4][4];
#pragma unroll
  for (int i = 0; i < 4; ++i)
#pragma unroll
    for (int j = 0; j < 4; ++j) acc[i][j] = (f32x4){0.f, 0.f, 0.f, 0.f};

#pragma unroll
  for (int kc = 0; kc < 2; ++kc) {
    // stage A chunk: 128 rows x 64 k (16 KB), 4 x uint4 per thread
#pragma unroll
    for (int p = 0; p < 4; ++p) {
      int f = tid + p * 256;
      int row = f >> 3, seg = f & 7;
      int gm = bm + row; if (gm >= M) gm = 0;
      *(uint4*)&As[row][seg * 8] = *(const uint4*)(Ab + (size_t)gm * 128 + kc * 64 + seg * 8);
    }
    // stage B chunk: 128 cols x 64 k
#pragma unroll
    for (int p = 0; p < 4; ++p) {
      int f = tid + p * 256;
      int row = f >> 3, seg = f & 7;
      *(uint4*)&Bs[row][seg * 8] = *(const uint4*)(Wt + (size_t)(bn + row) * 128 + kc * 64 + seg * 8);
    }
    __syncthreads();
#pragma unroll
    for (int ks = 0; ks < 2; ++ks) {
      short8 af[4], bf[4];
#pragma unroll
      for (int i = 0; i < 4; ++i) af[i] = *(short8*)&As[wy * 64 + i * 16 + lr][ks * 32 + q * 8];
#pragma unroll
      for (int j = 0; j < 4; ++j) bf[j] = *(short8*)&Bs[wx * 64 + j * 16 + lr][ks * 32 + q * 8];
#pragma unroll
      for (int i = 0; i < 4; ++i)
#pragma unroll
        for (int j = 0; j < 4; ++j)
          acc[i][j] = __builtin_amdgcn_mfma_f32_16x16x32_bf16(af[i], bf[j], acc[i][j], 0, 0, 0);
    }
    __syncthreads();
  }

  // epilogue: C/D layout col=lane&15, row=(lane>>4)*4+r
  float bj[4];
#pragma unroll
  for (int j = 0; j < 4; ++j) bj[j] = bcat[bn + wx * 64 + j * 16 + lr];
#pragma unroll
  for (int i = 0; i < 4; ++i) {
    int row = bm + wy * 64 + i * 16 + q * 4;
#pragma unroll
    for (int r = 0; r < 4; ++r) {
      int gr = row + r;
      if (gr >= M) continue;
#pragma unroll
      for (int j = 0; j < 4; ++j) {
        float val = acc[i][j][r] + bj[j];
        if (MODE == 0) {
          const int seg = blockIdx.y;
          const int lc = wx * 64 + j * 16 + lr;
          if (seg == 0)      Qout[(size_t)gr * 128 + lc] = val;
          else if (seg == 1) KV[(size_t)gr * 256 + (lc >> 1) * 4 + (lc & 1)] = f2bf(val);
          else if (seg == 2) KV[(size_t)gr * 256 + (lc >> 1) * 4 + 2 + (lc & 1)] = f2bf(val);
          else               Hout[(size_t)gr * 128 + lc] = val;
        } else {
          const int c = wx * 64 + j * 16 + lr;
          const int seg = c >> 5;
          const int lc = c & 31;
          if (seg == 0)      Qout[(size_t)gr * 32 + lc] = val;
          else if (seg == 1) KV[(size_t)gr * 64 + lc * 2] = f2bf(val);
          else if (seg == 2) KV[(size_t)gr * 64 + lc * 2 + 1] = f2bf(val);
          else               Hout[(size_t)gr * 32 + lc] = val;
        }
      }
    }
  }
}

// ---------------- CSR build ----------------
__global__ void deg_count(const int* __restrict__ ei, int* __restrict__ deg, int E) {
  int e = blockIdx.x * blockDim.x + threadIdx.x;
  if (e < E) atomicAdd(&deg[ei[E + e]], 1);
}

__global__ void scan_kernel(const int* __restrict__ deg, int* __restrict__ rowptr,
                            int* __restrict__ cur, int n) {
  __shared__ int s[1024];
  const int t = threadIdx.x;
  const int C = (n + 1023) / 1024;
  const int base = t * C;
  int sum = 0;
  for (int i = 0; i < C; ++i) {
    int idx = base + i;
    if (idx < n) sum += deg[idx];
  }
  s[t] = sum;
  __syncthreads();
  for (int off = 1; off < 1024; off <<= 1) {
    int v = (t >= off) ? s[t - off] : 0;
    __syncthreads();
    s[t] += v;
    __syncthreads();
  }
  int run = (t == 0) ? 0 : s[t - 1];
  for (int i = 0; i < C; ++i) {
    int idx = base + i;
    if (idx < n) {
      rowptr[idx] = run;
      cur[idx] = run;
      run += deg[idx];
    }
  }
  if (t == 1023) rowptr[n] = s[1023];
}

__global__ void scatter_edges(const int* __restrict__ ei, int* __restrict__ cur,
                              int* __restrict__ esrc, int E) {
  int e = blockIdx.x * blockDim.x + threadIdx.x;
  if (e >= E) return;
  int src = ei[e];
  int dst = ei[E + e];
  int pos = atomicAdd(&cur[dst], 1);
  esrc[pos] = src;
}

// ---------------- fused online-softmax aggregation ----------------
// conv1: one wave per node; lane owns dims 2l,2l+1; one 8B gather per edge per lane.
// Writes H fp32 (relu) and Hb bf16 (conv2 GEMM input).
__global__ void node_attn1(const int* __restrict__ rowptr, const int* __restrict__ esrc,
                           const float* __restrict__ Q, const unsigned short* __restrict__ KV,
                           float* __restrict__ H, unsigned short* __restrict__ Hb, int n) {
  int node = (blockIdx.x * blockDim.x + threadIdx.x) >> 6;
  int lane = threadIdx.x & 63;
  if (node >= n) return;
  const int r0 = rowptr[node], r1 = rowptr[node + 1];
  const float2 q = *(const float2*)(Q + (size_t)node * 128 + lane * 2);
  float m = -INFINITY, l = 0.f;
  float2 acc = {0.f, 0.f};
  for (int j = r0; j < r1; ++j) {
    int src = esrc[j];
    ushort4 kv = *(const ushort4*)(KV + (size_t)src * 256 + lane * 4);
    float kx = bf2f(kv.x), ky = bf2f(kv.y), vx = bf2f(kv.z), vy = bf2f(kv.w);
    float part = q.x * kx + q.y * ky;
    part += __shfl_xor(part, 1);
    part += __shfl_xor(part, 2);
    part += __shfl_xor(part, 4);
    part += __shfl_xor(part, 8);
    float lg = part * 0.17677669529663687f;  // 1/sqrt(32)
    float mnew = fmaxf(m, lg);
    float scale = __expf(m - mnew);
    float p = __expf(lg - mnew);
    l = l * scale + p;
    acc.x = acc.x * scale + p * vx;
    acc.y = acc.y * scale + p * vy;
    m = mnew;
  }
  float inv = (l > 0.f) ? 1.f / l : 0.f;
  float* h = H + (size_t)node * 128 + lane * 2;
  float2 skip = *(float2*)h;
  float2 o;
  o.x = fmaxf(skip.x + acc.x * inv, 0.f);
  o.y = fmaxf(skip.y + acc.y * inv, 0.f);
  *(float2*)h = o;
  unsigned hb = ((unsigned)f2bf(o.y) << 16) | (unsigned)f2bf(o.x);
  *(unsigned*)(Hb + (size_t)node * 128 + lane * 2) = hb;
}

// conv2: 32 lanes per node; one 4B gather per edge per lane (k,v interleaved).
__global__ void node_attn2(const int* __restrict__ rowptr, const int* __restrict__ esrc,
                           const float* __restrict__ Q, const unsigned short* __restrict__ KV,
                           float* __restrict__ H, int n) {
  int t = blockIdx.x * blockDim.x + threadIdx.x;
  int node = t >> 5;
  int lane = threadIdx.x & 31;
  if (node >= n) return;
  const int r0 = rowptr[node], r1 = rowptr[node + 1];
  const float q = Q[(size_t)node * 32 + lane];
  float m = -INFINITY, l = 0.f, acc = 0.f;
  for (int j = r0; j < r1; ++j) {
    int src = esrc[j];
    unsigned kvu = *(const unsigned*)(KV + (size_t)src * 64 + lane * 2);
    float k = __uint_as_float((kvu & 0xFFFFu) << 16);
    float v = __uint_as_float(kvu & 0xFFFF0000u);
    float part = q * k;
    part += __shfl_xor(part, 1);
    part += __shfl_xor(part, 2);
    part += __shfl_xor(part, 4);
    part += __shfl_xor(part, 8);
    part += __shfl_xor(part, 16);
    float lg = part * 0.17677669529663687f;
    float mnew = fmaxf(m, lg);
    float scale = __expf(m - mnew);
    float p = __expf(lg - mnew);
    l = l * scale + p;
    acc = acc * scale + p * v;
    m = mnew;
  }
  float inv = (l > 0.f) ? 1.f / l : 0.f;
  float* h = H + (size_t)node * 32 + lane;
  *h = *h + acc * inv;
}

// ---------------- epilogue ----------------
__global__ void mean_reduce(const float* __restrict__ H2, float* __restrict__ ACC, int total) {
  __shared__ float s[256];
  float acc = 0.f;
  int stride = gridDim.x * blockDim.x;
  for (int i = blockIdx.x * blockDim.x + threadIdx.x; i < total; i += stride)
    acc += fmaxf(H2[i], 0.f);  // relu fused
  s[threadIdx.x] = acc;
  __syncthreads();
  for (int off = 128; off >= 32; off >>= 1) {
    if (threadIdx.x < off) s[threadIdx.x] += s[threadIdx.x + off];
    __syncthreads();
  }
  if (threadIdx.x < 32) atomicAdd(&ACC[threadIdx.x], s[threadIdx.x]);
}

__global__ void final_out(const float* __restrict__ ACC, const float* __restrict__ Wo,
                          const float* __restrict__ bo, float* __restrict__ out, float invN) {
  int lane = threadIdx.x;
  float v = 0.f;
  if (lane < 32) v = ACC[lane] * invN * Wo[lane];
  v += __shfl_xor(v, 1);
  v += __shfl_xor(v, 2);
  v += __shfl_xor(v, 4);
  v += __shfl_xor(v, 8);
  v += __shfl_xor(v, 16);
  v += __shfl_xor(v, 32);
  if (lane == 0) out[0] = v + bo[0];
}

extern "C" void kernel_launch(void* const* d_in, const int* in_sizes, int n_in,
                              void* d_out, int out_size, void* d_ws, size_t ws_size,
                              hipStream_t stream) {
  const float* x   = (const float*)d_in[0];
  const int*   ei  = (const int*)d_in[1];  // [2, E]: row 0 = src, row 1 = dst
  const float* Wq1 = (const float*)d_in[2];  const float* bq1 = (const float*)d_in[3];
  const float* Wk1 = (const float*)d_in[4];  const float* bk1 = (const float*)d_in[5];
  const float* Wv1 = (const float*)d_in[6];  const float* bv1 = (const float*)d_in[7];
  const float* Ws1 = (const float*)d_in[8];  const float* bs1 = (const float*)d_in[9];
  const float* Wq2 = (const float*)d_in[10]; const float* bq2 = (const float*)d_in[11];
  const float* Wk2 = (const float*)d_in[12]; const float* bk2 = (const float*)d_in[13];
  const float* Wv2 = (const float*)d_in[14]; const float* bv2 = (const float*)d_in[15];
  const float* Ws2 = (const float*)d_in[16]; const float* bs2 = (const float*)d_in[17];
  const float* Wo  = (const float*)d_in[18]; const float* bo  = (const float*)d_in[19];

  char* ws = (char*)d_ws;
  const int N = N_NODES, E = N_EDGES;

  // conv1-phase buffers
  unsigned short* xb  = (unsigned short*)(ws + 0);          // N*128 bf16 (12.8 MB)
  float*          Q1  = (float*)(ws + 12800000);            // N*128 fp32
  float*          H1  = (float*)(ws + 38400000);            // N*128 fp32 (skip -> out)
  unsigned short* KV1 = (unsigned short*)(ws + 64000000);   // N*256 bf16 interleaved
  unsigned short* H1b = (unsigned short*)(ws + 89600000);   // N*128 bf16
  // conv2 buffers — overlay dead xb/Q1 region
  float*          Q2  = (float*)(ws + 0);                   // N*32 fp32
  float*          H2  = (float*)(ws + 6400000);             // N*32 fp32
  unsigned short* KV2 = (unsigned short*)(ws + 12800000);   // N*64 bf16 interleaved
  // CSR + weights + misc
  int* rowptr = (int*)(ws + 102400000);
  int* cur    = (int*)(ws + 102600064);
  int* esrc   = (int*)(ws + 102800128);
  int* deg    = (int*)(ws + 106000128);
  unsigned short* Wt1   = (unsigned short*)(ws + 106200192);  // 512x128 bf16
  unsigned short* Wt2   = (unsigned short*)(ws + 106331264);  // 128x128 bf16
  float*          bcat1 = (float*)(ws + 106364032);           // 512
  float*          bcat2 = (float*)(ws + 106366080);           // 128
  float*          ACC   = (float*)(ws + 106366592);           // 32

  float* out = (float*)d_out;

  hipMemsetAsync(deg, 0, (size_t)N * sizeof(int), stream);
  hipMemsetAsync(ACC, 0, 32 * sizeof(float), stream);

  dim3 blk(256);

  // ---- CSR build ----
  deg_count<<<dim3((E + 255) / 256), blk, 0, stream>>>(ei, deg, E);
  scan_kernel<<<dim3(1), dim3(1024), 0, stream>>>(deg, rowptr, cur, N);
  scatter_edges<<<dim3((E + 255) / 256), blk, 0, stream>>>(ei, cur, esrc, E);

  // ---- prep: x -> bf16, weights -> bf16 transposed concat ----
  cast_bf16<<<dim3((N * 128 / 4 + 255) / 256), blk, 0, stream>>>(x, xb, N * 128 / 4);
  concat_wt<<<dim3((512 * 128 + 255) / 256), blk, 0, stream>>>(
      Wq1, Wk1, Wv1, Ws1, bq1, bk1, bv1, bs1, Wt1, bcat1, 128, 128);
  concat_wt<<<dim3((128 * 128 + 255) / 256), blk, 0, stream>>>(
      Wq2, Wk2, Wv2, Ws2, bq2, bk2, bv2, bs2, Wt2, bcat2, 128, 32);

  // ---- conv1 MFMA linears: [N,128] @ [128,512] ----
  mfma_linear<0><<<dim3((N + 127) / 128, 4), blk, 0, stream>>>(
      xb, Wt1, bcat1, Q1, KV1, H1, N);

  // ---- conv1 fused attention + skip + relu (+ bf16 out) ----
  node_attn1<<<dim3((N * 64 + 255) / 256), blk, 0, stream>>>(rowptr, esrc, Q1, KV1, H1, H1b, N);

  // ---- conv2 MFMA linears: [N,128] @ [128,128] ----
  mfma_linear<1><<<dim3((N + 127) / 128, 1), blk, 0, stream>>>(
      H1b, Wt2, bcat2, Q2, KV2, H2, N);

  // ---- conv2 fused attention ----
  node_attn2<<<dim3((N * 32 + 255) / 256), blk, 0, stream>>>(rowptr, esrc, Q2, KV2, H2, N);

  // ---- relu + mean + final linear ----
  mean_reduce<<<dim3(1024), blk, 0, stream>>>(H2, ACC, N * 32);
  final_out<<<dim3(1), dim3(64), 0, stream>>>(ACC, Wo, bo, out, 1.0f / (float)N);
}

// Round 5
// 452.582 us; speedup vs baseline: 4.6825x; 1.2595x over previous
//
#include <hip/hip_runtime.h>
#include <math.h>

#define N_NODES 50000
#define N_EDGES 800000

typedef short short8 __attribute__((ext_vector_type(8)));
typedef float f32x4 __attribute__((ext_vector_type(4)));

// ---------------- bf16 helpers ----------------
__device__ inline unsigned short f2bf(float v) {
  unsigned u = __float_as_uint(v);
  u += 0x7FFFu + ((u >> 16) & 1u);  // round-to-nearest-even
  return (unsigned short)(u >> 16);
}
__device__ inline float bf2f(unsigned short b) {
  return __uint_as_float(((unsigned)b) << 16);
}

// ---------------- cast x -> bf16 ----------------
__global__ void cast_bf16(const float* __restrict__ in, unsigned short* __restrict__ out, int n4) {
  int i = blockIdx.x * blockDim.x + threadIdx.x;
  if (i >= n4) return;
  float4 v = ((const float4*)in)[i];
  ushort4 o;
  o.x = f2bf(v.x); o.y = f2bf(v.y); o.z = f2bf(v.z); o.w = f2bf(v.w);
  ((ushort4*)out)[i] = o;
}

// ---------------- weight concat + transpose + bf16 ----------------
__global__ void concat_wt(const float* __restrict__ W0, const float* __restrict__ W1,
                          const float* __restrict__ W2, const float* __restrict__ W3,
                          const float* __restrict__ b0, const float* __restrict__ b1,
                          const float* __restrict__ b2, const float* __restrict__ b3,
                          unsigned short* __restrict__ Wt, float* __restrict__ bcat,
                          int K, int segN) {
  int i = blockIdx.x * blockDim.x + threadIdx.x;
  int Ncat = 4 * segN;
  if (i < Ncat * K) {
    int c = i / K, k = i % K;
    int mi = c / segN, lc = c % segN;
    const float* W = (mi == 0) ? W0 : (mi == 1) ? W1 : (mi == 2) ? W2 : W3;
    Wt[i] = f2bf(W[(size_t)k * segN + lc]);
  }
  if (i < Ncat) {
    int mi = i / segN, lc = i % segN;
    const float* b = (mi == 0) ? b0 : (mi == 1) ? b1 : (mi == 2) ? b2 : b3;
    bcat[i] = b[lc];
  }
}

// ---------------- MFMA GEMM: [M,128] @ [128, 4*seg] with routed epilogue ----------------
template <int MODE>
__global__ __launch_bounds__(256) void mfma_linear(
    const unsigned short* __restrict__ Ab, const unsigned short* __restrict__ Wt,
    const float* __restrict__ bcat, float* __restrict__ Qout,
    unsigned short* __restrict__ KV, float* __restrict__ Hout, int M) {
  __shared__ __align__(16) unsigned short As[128][72];
  __shared__ __align__(16) unsigned short Bs[128][72];
  const int bm = blockIdx.x * 128;
  const int bn = blockIdx.y * 128;
  const int tid = threadIdx.x;
  const int wave = tid >> 6;
  const int lane = tid & 63;
  const int wx = wave & 1;
  const int wy = wave >> 1;
  const int lr = lane & 15;
  const int q = lane >> 4;

  f32x4 acc[4][4];
#pragma unroll
  for (int i = 0; i < 4; ++i)
#pragma unroll
    for (int j = 0; j < 4; ++j) acc[i][j] = (f32x4){0.f, 0.f, 0.f, 0.f};

#pragma unroll
  for (int kc = 0; kc < 2; ++kc) {
#pragma unroll
    for (int p = 0; p < 4; ++p) {
      int f = tid + p * 256;
      int row = f >> 3, seg = f & 7;
      int gm = bm + row; if (gm >= M) gm = 0;
      *(uint4*)&As[row][seg * 8] = *(const uint4*)(Ab + (size_t)gm * 128 + kc * 64 + seg * 8);
    }
#pragma unroll
    for (int p = 0; p < 4; ++p) {
      int f = tid + p * 256;
      int row = f >> 3, seg = f & 7;
      *(uint4*)&Bs[row][seg * 8] = *(const uint4*)(Wt + (size_t)(bn + row) * 128 + kc * 64 + seg * 8);
    }
    __syncthreads();
#pragma unroll
    for (int ks = 0; ks < 2; ++ks) {
      short8 af[4], bf[4];
#pragma unroll
      for (int i = 0; i < 4; ++i) af[i] = *(short8*)&As[wy * 64 + i * 16 + lr][ks * 32 + q * 8];
#pragma unroll
      for (int j = 0; j < 4; ++j) bf[j] = *(short8*)&Bs[wx * 64 + j * 16 + lr][ks * 32 + q * 8];
#pragma unroll
      for (int i = 0; i < 4; ++i)
#pragma unroll
        for (int j = 0; j < 4; ++j)
          acc[i][j] = __builtin_amdgcn_mfma_f32_16x16x32_bf16(af[i], bf[j], acc[i][j], 0, 0, 0);
    }
    __syncthreads();
  }

  float bj[4];
#pragma unroll
  for (int j = 0; j < 4; ++j) bj[j] = bcat[bn + wx * 64 + j * 16 + lr];
#pragma unroll
  for (int i = 0; i < 4; ++i) {
    int row = bm + wy * 64 + i * 16 + q * 4;
#pragma unroll
    for (int r = 0; r < 4; ++r) {
      int gr = row + r;
      if (gr >= M) continue;
#pragma unroll
      for (int j = 0; j < 4; ++j) {
        float val = acc[i][j][r] + bj[j];
        if (MODE == 0) {
          const int seg = blockIdx.y;
          const int lc = wx * 64 + j * 16 + lr;
          if (seg == 0)      Qout[(size_t)gr * 128 + lc] = val;
          else if (seg == 1) KV[(size_t)gr * 256 + (lc >> 1) * 4 + (lc & 1)] = f2bf(val);
          else if (seg == 2) KV[(size_t)gr * 256 + (lc >> 1) * 4 + 2 + (lc & 1)] = f2bf(val);
          else               Hout[(size_t)gr * 128 + lc] = val;
        } else {
          const int c = wx * 64 + j * 16 + lr;
          const int seg = c >> 5;
          const int lc = c & 31;
          if (seg == 0)      Qout[(size_t)gr * 32 + lc] = val;
          else if (seg == 1) KV[(size_t)gr * 64 + lc * 2] = f2bf(val);
          else if (seg == 2) KV[(size_t)gr * 64 + lc * 2 + 1] = f2bf(val);
          else               Hout[(size_t)gr * 32 + lc] = val;
        }
      }
    }
  }
}

// ---------------- CSR build ----------------
__global__ void deg_count(const int* __restrict__ ei, int* __restrict__ deg, int E) {
  int e = blockIdx.x * blockDim.x + threadIdx.x;
  if (e < E) atomicAdd(&deg[ei[E + e]], 1);
}

// hierarchical scan, phase 1: per-block (256 elems) sums
__global__ void scan_part(const int* __restrict__ deg, int* __restrict__ bsum, int n) {
  int i = blockIdx.x * 256 + threadIdx.x;
  int v = (i < n) ? deg[i] : 0;
#pragma unroll
  for (int off = 1; off < 64; off <<= 1) v += __shfl_xor(v, off);
  __shared__ int s[4];
  if ((threadIdx.x & 63) == 0) s[threadIdx.x >> 6] = v;
  __syncthreads();
  if (threadIdx.x == 0) bsum[blockIdx.x] = s[0] + s[1] + s[2] + s[3];
}

// phase 2: single block scans <=256 block sums in LDS; writes rowptr[n]=total
__global__ void scan_tops(const int* __restrict__ bsum, int* __restrict__ boff,
                          int* __restrict__ rowptr, int nb, int n) {
  __shared__ int s[256];
  int t = threadIdx.x;
  int v = (t < nb) ? bsum[t] : 0;
  s[t] = v;
  __syncthreads();
#pragma unroll
  for (int off = 1; off < 256; off <<= 1) {
    int u = (t >= off) ? s[t - off] : 0;
    __syncthreads();
    s[t] += u;
    __syncthreads();
  }
  if (t < nb) boff[t] = (t == 0) ? 0 : s[t - 1];
  if (t == 255) rowptr[n] = s[255];
}

// phase 3: per-block exclusive scan + block offset -> rowptr, cur
__global__ void scan_final(const int* __restrict__ deg, const int* __restrict__ boff,
                           int* __restrict__ rowptr, int* __restrict__ cur, int n) {
  __shared__ int s[256];
  int i = blockIdx.x * 256 + threadIdx.x;
  int t = threadIdx.x;
  int v = (i < n) ? deg[i] : 0;
  s[t] = v;
  __syncthreads();
#pragma unroll
  for (int off = 1; off < 256; off <<= 1) {
    int u = (t >= off) ? s[t - off] : 0;
    __syncthreads();
    s[t] += u;
    __syncthreads();
  }
  if (i < n) {
    int excl = boff[blockIdx.x] + s[t] - v;
    rowptr[i] = excl;
    cur[i] = excl;
  }
}

__global__ void scatter_edges(const int* __restrict__ ei, int* __restrict__ cur,
                              int* __restrict__ esrc, int E) {
  int e = blockIdx.x * blockDim.x + threadIdx.x;
  if (e >= E) return;
  int src = ei[e];
  int dst = ei[E + e];
  int pos = atomicAdd(&cur[dst], 1);
  esrc[pos] = src;
}

// ---------------- fused online-softmax aggregation ----------------
__global__ void node_attn1(const int* __restrict__ rowptr, const int* __restrict__ esrc,
                           const float* __restrict__ Q, const unsigned short* __restrict__ KV,
                           float* __restrict__ H, unsigned short* __restrict__ Hb, int n) {
  int node = (blockIdx.x * blockDim.x + threadIdx.x) >> 6;
  int lane = threadIdx.x & 63;
  if (node >= n) return;
  const int r0 = rowptr[node], r1 = rowptr[node + 1];
  const float2 q = *(const float2*)(Q + (size_t)node * 128 + lane * 2);
  float m = -INFINITY, l = 0.f;
  float2 acc = {0.f, 0.f};
  for (int j = r0; j < r1; ++j) {
    int src = esrc[j];
    ushort4 kv = *(const ushort4*)(KV + (size_t)src * 256 + lane * 4);
    float kx = bf2f(kv.x), ky = bf2f(kv.y), vx = bf2f(kv.z), vy = bf2f(kv.w);
    float part = q.x * kx + q.y * ky;
    part += __shfl_xor(part, 1);
    part += __shfl_xor(part, 2);
    part += __shfl_xor(part, 4);
    part += __shfl_xor(part, 8);
    float lg = part * 0.17677669529663687f;  // 1/sqrt(32)
    float mnew = fmaxf(m, lg);
    float scale = __expf(m - mnew);
    float p = __expf(lg - mnew);
    l = l * scale + p;
    acc.x = acc.x * scale + p * vx;
    acc.y = acc.y * scale + p * vy;
    m = mnew;
  }
  float inv = (l > 0.f) ? 1.f / l : 0.f;
  float* h = H + (size_t)node * 128 + lane * 2;
  float2 skip = *(float2*)h;
  float2 o;
  o.x = fmaxf(skip.x + acc.x * inv, 0.f);
  o.y = fmaxf(skip.y + acc.y * inv, 0.f);
  *(float2*)h = o;
  unsigned hb = ((unsigned)f2bf(o.y) << 16) | (unsigned)f2bf(o.x);
  *(unsigned*)(Hb + (size_t)node * 128 + lane * 2) = hb;
}

__global__ void node_attn2(const int* __restrict__ rowptr, const int* __restrict__ esrc,
                           const float* __restrict__ Q, const unsigned short* __restrict__ KV,
                           float* __restrict__ H, int n) {
  int t = blockIdx.x * blockDim.x + threadIdx.x;
  int node = t >> 5;
  int lane = threadIdx.x & 31;
  if (node >= n) return;
  const int r0 = rowptr[node], r1 = rowptr[node + 1];
  const float q = Q[(size_t)node * 32 + lane];
  float m = -INFINITY, l = 0.f, acc = 0.f;
  for (int j = r0; j < r1; ++j) {
    int src = esrc[j];
    unsigned kvu = *(const unsigned*)(KV + (size_t)src * 64 + lane * 2);
    float k = __uint_as_float((kvu & 0xFFFFu) << 16);
    float v = __uint_as_float(kvu & 0xFFFF0000u);
    float part = q * k;
    part += __shfl_xor(part, 1);
    part += __shfl_xor(part, 2);
    part += __shfl_xor(part, 4);
    part += __shfl_xor(part, 8);
    part += __shfl_xor(part, 16);
    float lg = part * 0.17677669529663687f;
    float mnew = fmaxf(m, lg);
    float scale = __expf(m - mnew);
    float p = __expf(lg - mnew);
    l = l * scale + p;
    acc = acc * scale + p * v;
    m = mnew;
  }
  float inv = (l > 0.f) ? 1.f / l : 0.f;
  float* h = H + (size_t)node * 32 + lane;
  *h = *h + acc * inv;
}

// ---------------- epilogue ----------------
__global__ void mean_reduce(const float* __restrict__ H2, float* __restrict__ ACC, int total) {
  __shared__ float s[256];
  float acc = 0.f;
  int stride = gridDim.x * blockDim.x;
  for (int i = blockIdx.x * blockDim.x + threadIdx.x; i < total; i += stride)
    acc += fmaxf(H2[i], 0.f);  // relu fused
  s[threadIdx.x] = acc;
  __syncthreads();
  for (int off = 128; off >= 32; off >>= 1) {
    if (threadIdx.x < off) s[threadIdx.x] += s[threadIdx.x + off];
    __syncthreads();
  }
  if (threadIdx.x < 32) atomicAdd(&ACC[threadIdx.x], s[threadIdx.x]);
}

__global__ void final_out(const float* __restrict__ ACC, const float* __restrict__ Wo,
                          const float* __restrict__ bo, float* __restrict__ out, float invN) {
  int lane = threadIdx.x;
  float v = 0.f;
  if (lane < 32) v = ACC[lane] * invN * Wo[lane];
  v += __shfl_xor(v, 1);
  v += __shfl_xor(v, 2);
  v += __shfl_xor(v, 4);
  v += __shfl_xor(v, 8);
  v += __shfl_xor(v, 16);
  v += __shfl_xor(v, 32);
  if (lane == 0) out[0] = v + bo[0];
}

extern "C" void kernel_launch(void* const* d_in, const int* in_sizes, int n_in,
                              void* d_out, int out_size, void* d_ws, size_t ws_size,
                              hipStream_t stream) {
  const float* x   = (const float*)d_in[0];
  const int*   ei  = (const int*)d_in[1];  // [2, E]: row 0 = src, row 1 = dst
  const float* Wq1 = (const float*)d_in[2];  const float* bq1 = (const float*)d_in[3];
  const float* Wk1 = (const float*)d_in[4];  const float* bk1 = (const float*)d_in[5];
  const float* Wv1 = (const float*)d_in[6];  const float* bv1 = (const float*)d_in[7];
  const float* Ws1 = (const float*)d_in[8];  const float* bs1 = (const float*)d_in[9];
  const float* Wq2 = (const float*)d_in[10]; const float* bq2 = (const float*)d_in[11];
  const float* Wk2 = (const float*)d_in[12]; const float* bk2 = (const float*)d_in[13];
  const float* Wv2 = (const float*)d_in[14]; const float* bv2 = (const float*)d_in[15];
  const float* Ws2 = (const float*)d_in[16]; const float* bs2 = (const float*)d_in[17];
  const float* Wo  = (const float*)d_in[18]; const float* bo  = (const float*)d_in[19];

  char* ws = (char*)d_ws;
  const int N = N_NODES, E = N_EDGES;
  const int NB = (N + 255) / 256;  // 196 scan blocks

  // conv1-phase buffers
  unsigned short* xb  = (unsigned short*)(ws + 0);          // N*128 bf16
  float*          Q1  = (float*)(ws + 12800000);            // N*128 fp32
  float*          H1  = (float*)(ws + 38400000);            // N*128 fp32
  unsigned short* KV1 = (unsigned short*)(ws + 64000000);   // N*256 bf16 interleaved
  unsigned short* H1b = (unsigned short*)(ws + 89600000);   // N*128 bf16
  // conv2 buffers — overlay dead xb/Q1 region
  float*          Q2  = (float*)(ws + 0);                   // N*32 fp32
  float*          H2  = (float*)(ws + 6400000);             // N*32 fp32
  unsigned short* KV2 = (unsigned short*)(ws + 12800000);   // N*64 bf16 interleaved
  // CSR + weights + misc
  int* rowptr = (int*)(ws + 102400000);
  int* cur    = (int*)(ws + 102600064);
  int* esrc   = (int*)(ws + 102800128);
  int* deg    = (int*)(ws + 106000128);
  int* bsum   = (int*)(ws + 106200192);                       // 256
  int* boff   = (int*)(ws + 106201216);                       // 256
  unsigned short* Wt1   = (unsigned short*)(ws + 106202240);  // 512x128 bf16
  unsigned short* Wt2   = (unsigned short*)(ws + 106333312);  // 128x128 bf16
  float*          bcat1 = (float*)(ws + 106366080);           // 512
  float*          bcat2 = (float*)(ws + 106368128);           // 128
  float*          ACC   = (float*)(ws + 106368640);           // 32

  float* out = (float*)d_out;

  hipMemsetAsync(deg, 0, (size_t)N * sizeof(int), stream);
  hipMemsetAsync(ACC, 0, 32 * sizeof(float), stream);

  dim3 blk(256);

  // ---- CSR build (hierarchical scan) ----
  deg_count<<<dim3((E + 255) / 256), blk, 0, stream>>>(ei, deg, E);
  scan_part<<<dim3(NB), blk, 0, stream>>>(deg, bsum, N);
  scan_tops<<<dim3(1), blk, 0, stream>>>(bsum, boff, rowptr, NB, N);
  scan_final<<<dim3(NB), blk, 0, stream>>>(deg, boff, rowptr, cur, N);
  scatter_edges<<<dim3((E + 255) / 256), blk, 0, stream>>>(ei, cur, esrc, E);

  // ---- prep: x -> bf16, weights -> bf16 transposed concat ----
  cast_bf16<<<dim3((N * 128 / 4 + 255) / 256), blk, 0, stream>>>(x, xb, N * 128 / 4);
  concat_wt<<<dim3((512 * 128 + 255) / 256), blk, 0, stream>>>(
      Wq1, Wk1, Wv1, Ws1, bq1, bk1, bv1, bs1, Wt1, bcat1, 128, 128);
  concat_wt<<<dim3((128 * 128 + 255) / 256), blk, 0, stream>>>(
      Wq2, Wk2, Wv2, Ws2, bq2, bk2, bv2, bs2, Wt2, bcat2, 128, 32);

  // ---- conv1 MFMA linears: [N,128] @ [128,512] ----
  mfma_linear<0><<<dim3((N + 127) / 128, 4), blk, 0, stream>>>(
      xb, Wt1, bcat1, Q1, KV1, H1, N);

  // ---- conv1 fused attention + skip + relu (+ bf16 out) ----
  node_attn1<<<dim3((N * 64 + 255) / 256), blk, 0, stream>>>(rowptr, esrc, Q1, KV1, H1, H1b, N);

  // ---- conv2 MFMA linears: [N,128] @ [128,128] ----
  mfma_linear<1><<<dim3((N + 127) / 128, 1), blk, 0, stream>>>(
      H1b, Wt2, bcat2, Q2, KV2, H2, N);

  // ---- conv2 fused attention ----
  node_attn2<<<dim3((N * 32 + 255) / 256), blk, 0, stream>>>(rowptr, esrc, Q2, KV2, H2, N);

  // ---- relu + mean + final linear ----
  mean_reduce<<<dim3(1024), blk, 0, stream>>>(H2, ACC, N * 32);
  final_out<<<dim3(1), dim3(64), 0, stream>>>(ACC, Wo, bo, out, 1.0f / (float)N);
}

// Round 6
// 377.495 us; speedup vs baseline: 5.6138x; 1.1989x over previous
//
#include <hip/hip_runtime.h>
#include <math.h>

#define N_NODES 50000
#define N_EDGES 800000

typedef short short8 __attribute__((ext_vector_type(8)));
typedef float f32x4 __attribute__((ext_vector_type(4)));

// ---------------- bf16 helpers ----------------
__device__ inline unsigned short f2bf(float v) {
  unsigned u = __float_as_uint(v);
  u += 0x7FFFu + ((u >> 16) & 1u);  // round-to-nearest-even
  return (unsigned short)(u >> 16);
}
__device__ inline float bf2f(unsigned short b) {
  return __uint_as_float(((unsigned)b) << 16);
}

// ---------------- cast x -> bf16 ----------------
__global__ void cast_bf16(const float* __restrict__ in, unsigned short* __restrict__ out, int n4) {
  int i = blockIdx.x * blockDim.x + threadIdx.x;
  if (i >= n4) return;
  float4 v = ((const float4*)in)[i];
  ushort4 o;
  o.x = f2bf(v.x); o.y = f2bf(v.y); o.z = f2bf(v.z); o.w = f2bf(v.w);
  ((ushort4*)out)[i] = o;
}

// ---------------- weight concat + transpose + bf16 ----------------
__global__ void concat_wt(const float* __restrict__ W0, const float* __restrict__ W1,
                          const float* __restrict__ W2, const float* __restrict__ W3,
                          const float* __restrict__ b0, const float* __restrict__ b1,
                          const float* __restrict__ b2, const float* __restrict__ b3,
                          unsigned short* __restrict__ Wt, float* __restrict__ bcat,
                          int K, int segN) {
  int i = blockIdx.x * blockDim.x + threadIdx.x;
  int Ncat = 4 * segN;
  if (i < Ncat * K) {
    int c = i / K, k = i % K;
    int mi = c / segN, lc = c % segN;
    const float* W = (mi == 0) ? W0 : (mi == 1) ? W1 : (mi == 2) ? W2 : W3;
    Wt[i] = f2bf(W[(size_t)k * segN + lc]);
  }
  if (i < Ncat) {
    int mi = i / segN, lc = i % segN;
    const float* b = (mi == 0) ? b0 : (mi == 1) ? b1 : (mi == 2) ? b2 : b3;
    bcat[i] = b[lc];
  }
}

// ---------------- MFMA GEMM: [M,128] @ [128, 4*seg] with routed epilogue ----------------
// MODE 0 (conv1): blockIdx.y = segment (0=Q fp32, 1=K->KV, 2=V->KV, 3=skip->SK bf16).
// MODE 1 (conv2): segment = col>>5 (0=Q fp32, 1=K->KV, 2=V->KV, 3=skip->H fp32).
template <int MODE>
__global__ __launch_bounds__(256) void mfma_linear(
    const unsigned short* __restrict__ Ab, const unsigned short* __restrict__ Wt,
    const float* __restrict__ bcat, float* __restrict__ Qout,
    unsigned short* __restrict__ KV, unsigned short* __restrict__ SKout,
    float* __restrict__ Hout, int M) {
  __shared__ __align__(16) unsigned short As[128][72];
  __shared__ __align__(16) unsigned short Bs[128][72];
  const int bm = blockIdx.x * 128;
  const int bn = blockIdx.y * 128;
  const int tid = threadIdx.x;
  const int wave = tid >> 6;
  const int lane = tid & 63;
  const int wx = wave & 1;
  const int wy = wave >> 1;
  const int lr = lane & 15;
  const int q = lane >> 4;

  f32x4 acc[4][4];
#pragma unroll
  for (int i = 0; i < 4; ++i)
#pragma unroll
    for (int j = 0; j < 4; ++j) acc[i][j] = (f32x4){0.f, 0.f, 0.f, 0.f};

#pragma unroll
  for (int kc = 0; kc < 2; ++kc) {
#pragma unroll
    for (int p = 0; p < 4; ++p) {
      int f = tid + p * 256;
      int row = f >> 3, seg = f & 7;
      int gm = bm + row; if (gm >= M) gm = 0;
      *(uint4*)&As[row][seg * 8] = *(const uint4*)(Ab + (size_t)gm * 128 + kc * 64 + seg * 8);
    }
#pragma unroll
    for (int p = 0; p < 4; ++p) {
      int f = tid + p * 256;
      int row = f >> 3, seg = f & 7;
      *(uint4*)&Bs[row][seg * 8] = *(const uint4*)(Wt + (size_t)(bn + row) * 128 + kc * 64 + seg * 8);
    }
    __syncthreads();
#pragma unroll
    for (int ks = 0; ks < 2; ++ks) {
      short8 af[4], bf[4];
#pragma unroll
      for (int i = 0; i < 4; ++i) af[i] = *(short8*)&As[wy * 64 + i * 16 + lr][ks * 32 + q * 8];
#pragma unroll
      for (int j = 0; j < 4; ++j) bf[j] = *(short8*)&Bs[wx * 64 + j * 16 + lr][ks * 32 + q * 8];
#pragma unroll
      for (int i = 0; i < 4; ++i)
#pragma unroll
        for (int j = 0; j < 4; ++j)
          acc[i][j] = __builtin_amdgcn_mfma_f32_16x16x32_bf16(af[i], bf[j], acc[i][j], 0, 0, 0);
    }
    __syncthreads();
  }

  float bj[4];
#pragma unroll
  for (int j = 0; j < 4; ++j) bj[j] = bcat[bn + wx * 64 + j * 16 + lr];
#pragma unroll
  for (int i = 0; i < 4; ++i) {
    int row = bm + wy * 64 + i * 16 + q * 4;
#pragma unroll
    for (int r = 0; r < 4; ++r) {
      int gr = row + r;
      if (gr >= M) continue;
#pragma unroll
      for (int j = 0; j < 4; ++j) {
        float val = acc[i][j][r] + bj[j];
        if (MODE == 0) {
          const int seg = blockIdx.y;
          const int lc = wx * 64 + j * 16 + lr;
          if (seg == 0)      Qout[(size_t)gr * 128 + lc] = val;
          else if (seg == 1) KV[(size_t)gr * 256 + (lc >> 1) * 4 + (lc & 1)] = f2bf(val);
          else if (seg == 2) KV[(size_t)gr * 256 + (lc >> 1) * 4 + 2 + (lc & 1)] = f2bf(val);
          else               SKout[(size_t)gr * 128 + lc] = f2bf(val);
        } else {
          const int c = wx * 64 + j * 16 + lr;
          const int seg = c >> 5;
          const int lc = c & 31;
          if (seg == 0)      Qout[(size_t)gr * 32 + lc] = val;
          else if (seg == 1) KV[(size_t)gr * 64 + lc * 2] = f2bf(val);
          else if (seg == 2) KV[(size_t)gr * 64 + lc * 2 + 1] = f2bf(val);
          else               Hout[(size_t)gr * 32 + lc] = val;
        }
      }
    }
  }
}

// ---------------- CSR build ----------------
__global__ void deg_count(const int* __restrict__ ei, int* __restrict__ deg, int E) {
  int e = blockIdx.x * blockDim.x + threadIdx.x;
  if (e < E) atomicAdd(&deg[ei[E + e]], 1);
}

__global__ void scan_part(const int* __restrict__ deg, int* __restrict__ bsum, int n) {
  int i = blockIdx.x * 256 + threadIdx.x;
  int v = (i < n) ? deg[i] : 0;
#pragma unroll
  for (int off = 1; off < 64; off <<= 1) v += __shfl_xor(v, off);
  __shared__ int s[4];
  if ((threadIdx.x & 63) == 0) s[threadIdx.x >> 6] = v;
  __syncthreads();
  if (threadIdx.x == 0) bsum[blockIdx.x] = s[0] + s[1] + s[2] + s[3];
}

__global__ void scan_tops(const int* __restrict__ bsum, int* __restrict__ boff,
                          int* __restrict__ rowptr, int nb, int n) {
  __shared__ int s[256];
  int t = threadIdx.x;
  int v = (t < nb) ? bsum[t] : 0;
  s[t] = v;
  __syncthreads();
#pragma unroll
  for (int off = 1; off < 256; off <<= 1) {
    int u = (t >= off) ? s[t - off] : 0;
    __syncthreads();
    s[t] += u;
    __syncthreads();
  }
  if (t < nb) boff[t] = (t == 0) ? 0 : s[t - 1];
  if (t == 255) rowptr[n] = s[255];
}

__global__ void scan_final(const int* __restrict__ deg, const int* __restrict__ boff,
                           int* __restrict__ rowptr, int* __restrict__ cur, int n) {
  __shared__ int s[256];
  int i = blockIdx.x * 256 + threadIdx.x;
  int t = threadIdx.x;
  int v = (i < n) ? deg[i] : 0;
  s[t] = v;
  __syncthreads();
#pragma unroll
  for (int off = 1; off < 256; off <<= 1) {
    int u = (t >= off) ? s[t - off] : 0;
    __syncthreads();
    s[t] += u;
    __syncthreads();
  }
  if (i < n) {
    int excl = boff[blockIdx.x] + s[t] - v;
    rowptr[i] = excl;
    cur[i] = excl;
  }
}

__global__ void scatter_edges(const int* __restrict__ ei, int* __restrict__ cur,
                              int* __restrict__ esrc, int E) {
  int e = blockIdx.x * blockDim.x + threadIdx.x;
  if (e >= E) return;
  int src = ei[e];
  int dst = ei[E + e];
  int pos = atomicAdd(&cur[dst], 1);
  esrc[pos] = src;
}

// ---------------- fused online-softmax aggregation ----------------
// conv1: one wave per node; lane owns 2 dims. Edge loop unrolled x4:
// 4 independent gather->dot->swizzle chains, one softmax rescale per chunk.
__global__ void node_attn1(const int* __restrict__ rowptr, const int* __restrict__ esrc,
                           const float* __restrict__ Q, const unsigned short* __restrict__ KV,
                           const unsigned short* __restrict__ SK, unsigned short* __restrict__ Hb,
                           int n) {
  int node = (blockIdx.x * blockDim.x + threadIdx.x) >> 6;
  int lane = threadIdx.x & 63;
  if (node >= n) return;
  const int r0 = rowptr[node], r1 = rowptr[node + 1];
  const float2 q = *(const float2*)(Q + (size_t)node * 128 + lane * 2);
  float m = -INFINITY, l = 0.f;
  float2 acc = {0.f, 0.f};
  const float SCL = 0.17677669529663687f;  // 1/sqrt(32)
  int j = r0;
  for (; j + 4 <= r1; j += 4) {
    int s0 = esrc[j], s1 = esrc[j + 1], s2 = esrc[j + 2], s3 = esrc[j + 3];
    ushort4 kv0 = *(const ushort4*)(KV + (size_t)s0 * 256 + lane * 4);
    ushort4 kv1 = *(const ushort4*)(KV + (size_t)s1 * 256 + lane * 4);
    ushort4 kv2 = *(const ushort4*)(KV + (size_t)s2 * 256 + lane * 4);
    ushort4 kv3 = *(const ushort4*)(KV + (size_t)s3 * 256 + lane * 4);
    float d0 = q.x * bf2f(kv0.x) + q.y * bf2f(kv0.y);
    float d1 = q.x * bf2f(kv1.x) + q.y * bf2f(kv1.y);
    float d2 = q.x * bf2f(kv2.x) + q.y * bf2f(kv2.y);
    float d3 = q.x * bf2f(kv3.x) + q.y * bf2f(kv3.y);
#pragma unroll
    for (int msk = 1; msk <= 8; msk <<= 1) {
      d0 += __shfl_xor(d0, msk);
      d1 += __shfl_xor(d1, msk);
      d2 += __shfl_xor(d2, msk);
      d3 += __shfl_xor(d3, msk);
    }
    float lg0 = d0 * SCL, lg1 = d1 * SCL, lg2 = d2 * SCL, lg3 = d3 * SCL;
    float mnew = fmaxf(fmaxf(m, fmaxf(lg0, lg1)), fmaxf(lg2, lg3));
    float sc = __expf(m - mnew);
    float p0 = __expf(lg0 - mnew), p1 = __expf(lg1 - mnew);
    float p2 = __expf(lg2 - mnew), p3 = __expf(lg3 - mnew);
    l = l * sc + (p0 + p1) + (p2 + p3);
    acc.x = acc.x * sc + p0 * bf2f(kv0.z) + p1 * bf2f(kv1.z) + p2 * bf2f(kv2.z) + p3 * bf2f(kv3.z);
    acc.y = acc.y * sc + p0 * bf2f(kv0.w) + p1 * bf2f(kv1.w) + p2 * bf2f(kv2.w) + p3 * bf2f(kv3.w);
    m = mnew;
  }
  for (; j < r1; ++j) {
    int src = esrc[j];
    ushort4 kv = *(const ushort4*)(KV + (size_t)src * 256 + lane * 4);
    float d = q.x * bf2f(kv.x) + q.y * bf2f(kv.y);
    d += __shfl_xor(d, 1);
    d += __shfl_xor(d, 2);
    d += __shfl_xor(d, 4);
    d += __shfl_xor(d, 8);
    float lg = d * SCL;
    float mnew = fmaxf(m, lg);
    float sc = __expf(m - mnew);
    float p = __expf(lg - mnew);
    l = l * sc + p;
    acc.x = acc.x * sc + p * bf2f(kv.z);
    acc.y = acc.y * sc + p * bf2f(kv.w);
    m = mnew;
  }
  float inv = (l > 0.f) ? 1.f / l : 0.f;
  unsigned sku = *(const unsigned*)(SK + (size_t)node * 128 + lane * 2);
  float skx = __uint_as_float((sku & 0xFFFFu) << 16);
  float sky = __uint_as_float(sku & 0xFFFF0000u);
  float ox = fmaxf(skx + acc.x * inv, 0.f);
  float oy = fmaxf(sky + acc.y * inv, 0.f);
  unsigned hb = ((unsigned)f2bf(oy) << 16) | (unsigned)f2bf(ox);
  *(unsigned*)(Hb + (size_t)node * 128 + lane * 2) = hb;
}

// conv2: 32 lanes per node; edge loop unrolled x4.
__global__ void node_attn2(const int* __restrict__ rowptr, const int* __restrict__ esrc,
                           const float* __restrict__ Q, const unsigned short* __restrict__ KV,
                           float* __restrict__ H, int n) {
  int t = blockIdx.x * blockDim.x + threadIdx.x;
  int node = t >> 5;
  int lane = threadIdx.x & 31;
  if (node >= n) return;
  const int r0 = rowptr[node], r1 = rowptr[node + 1];
  const float q = Q[(size_t)node * 32 + lane];
  float m = -INFINITY, l = 0.f, acc = 0.f;
  const float SCL = 0.17677669529663687f;
  int j = r0;
  for (; j + 4 <= r1; j += 4) {
    int s0 = esrc[j], s1 = esrc[j + 1], s2 = esrc[j + 2], s3 = esrc[j + 3];
    unsigned u0 = *(const unsigned*)(KV + (size_t)s0 * 64 + lane * 2);
    unsigned u1 = *(const unsigned*)(KV + (size_t)s1 * 64 + lane * 2);
    unsigned u2 = *(const unsigned*)(KV + (size_t)s2 * 64 + lane * 2);
    unsigned u3 = *(const unsigned*)(KV + (size_t)s3 * 64 + lane * 2);
    float d0 = q * __uint_as_float((u0 & 0xFFFFu) << 16);
    float d1 = q * __uint_as_float((u1 & 0xFFFFu) << 16);
    float d2 = q * __uint_as_float((u2 & 0xFFFFu) << 16);
    float d3 = q * __uint_as_float((u3 & 0xFFFFu) << 16);
#pragma unroll
    for (int msk = 1; msk <= 16; msk <<= 1) {
      d0 += __shfl_xor(d0, msk);
      d1 += __shfl_xor(d1, msk);
      d2 += __shfl_xor(d2, msk);
      d3 += __shfl_xor(d3, msk);
    }
    float lg0 = d0 * SCL, lg1 = d1 * SCL, lg2 = d2 * SCL, lg3 = d3 * SCL;
    float mnew = fmaxf(fmaxf(m, fmaxf(lg0, lg1)), fmaxf(lg2, lg3));
    float sc = __expf(m - mnew);
    float p0 = __expf(lg0 - mnew), p1 = __expf(lg1 - mnew);
    float p2 = __expf(lg2 - mnew), p3 = __expf(lg3 - mnew);
    l = l * sc + (p0 + p1) + (p2 + p3);
    acc = acc * sc + p0 * __uint_as_float(u0 & 0xFFFF0000u) + p1 * __uint_as_float(u1 & 0xFFFF0000u)
                   + p2 * __uint_as_float(u2 & 0xFFFF0000u) + p3 * __uint_as_float(u3 & 0xFFFF0000u);
    m = mnew;
  }
  for (; j < r1; ++j) {
    int src = esrc[j];
    unsigned kvu = *(const unsigned*)(KV + (size_t)src * 64 + lane * 2);
    float k = __uint_as_float((kvu & 0xFFFFu) << 16);
    float v = __uint_as_float(kvu & 0xFFFF0000u);
    float d = q * k;
    d += __shfl_xor(d, 1);
    d += __shfl_xor(d, 2);
    d += __shfl_xor(d, 4);
    d += __shfl_xor(d, 8);
    d += __shfl_xor(d, 16);
    float lg = d * SCL;
    float mnew = fmaxf(m, lg);
    float sc = __expf(m - mnew);
    float p = __expf(lg - mnew);
    l = l * sc + p;
    acc = acc * sc + p * v;
    m = mnew;
  }
  float inv = (l > 0.f) ? 1.f / l : 0.f;
  float* h = H + (size_t)node * 32 + lane;
  *h = *h + acc * inv;
}

// ---------------- epilogue ----------------
__global__ void mean_reduce(const float* __restrict__ H2, float* __restrict__ ACC, int total) {
  __shared__ float s[256];
  float acc = 0.f;
  int stride = gridDim.x * blockDim.x;
  for (int i = blockIdx.x * blockDim.x + threadIdx.x; i < total; i += stride)
    acc += fmaxf(H2[i], 0.f);  // relu fused
  s[threadIdx.x] = acc;
  __syncthreads();
  for (int off = 128; off >= 32; off >>= 1) {
    if (threadIdx.x < off) s[threadIdx.x] += s[threadIdx.x + off];
    __syncthreads();
  }
  if (threadIdx.x < 32) atomicAdd(&ACC[threadIdx.x], s[threadIdx.x]);
}

__global__ void final_out(const float* __restrict__ ACC, const float* __restrict__ Wo,
                          const float* __restrict__ bo, float* __restrict__ out, float invN) {
  int lane = threadIdx.x;
  float v = 0.f;
  if (lane < 32) v = ACC[lane] * invN * Wo[lane];
  v += __shfl_xor(v, 1);
  v += __shfl_xor(v, 2);
  v += __shfl_xor(v, 4);
  v += __shfl_xor(v, 8);
  v += __shfl_xor(v, 16);
  v += __shfl_xor(v, 32);
  if (lane == 0) out[0] = v + bo[0];
}

extern "C" void kernel_launch(void* const* d_in, const int* in_sizes, int n_in,
                              void* d_out, int out_size, void* d_ws, size_t ws_size,
                              hipStream_t stream) {
  const float* x   = (const float*)d_in[0];
  const int*   ei  = (const int*)d_in[1];  // [2, E]: row 0 = src, row 1 = dst
  const float* Wq1 = (const float*)d_in[2];  const float* bq1 = (const float*)d_in[3];
  const float* Wk1 = (const float*)d_in[4];  const float* bk1 = (const float*)d_in[5];
  const float* Wv1 = (const float*)d_in[6];  const float* bv1 = (const float*)d_in[7];
  const float* Ws1 = (const float*)d_in[8];  const float* bs1 = (const float*)d_in[9];
  const float* Wq2 = (const float*)d_in[10]; const float* bq2 = (const float*)d_in[11];
  const float* Wk2 = (const float*)d_in[12]; const float* bk2 = (const float*)d_in[13];
  const float* Wv2 = (const float*)d_in[14]; const float* bv2 = (const float*)d_in[15];
  const float* Ws2 = (const float*)d_in[16]; const float* bs2 = (const float*)d_in[17];
  const float* Wo  = (const float*)d_in[18]; const float* bo  = (const float*)d_in[19];

  char* ws = (char*)d_ws;
  const int N = N_NODES, E = N_EDGES;
  const int NB = (N + 255) / 256;

  // conv1-phase buffers
  unsigned short* xb  = (unsigned short*)(ws + 0);          // N*128 bf16
  float*          Q1  = (float*)(ws + 12800000);            // N*128 fp32
  unsigned short* SK1 = (unsigned short*)(ws + 38400000);   // N*128 bf16 skip
  unsigned short* KV1 = (unsigned short*)(ws + 64000000);   // N*256 bf16 interleaved
  unsigned short* H1b = (unsigned short*)(ws + 89600000);   // N*128 bf16
  // conv2 buffers — overlay dead xb/Q1 regions
  float*          Q2  = (float*)(ws + 0);                   // N*32 fp32
  float*          H2  = (float*)(ws + 6400000);             // N*32 fp32
  unsigned short* KV2 = (unsigned short*)(ws + 12800000);   // N*64 bf16 interleaved
  // CSR + weights + misc
  int* rowptr = (int*)(ws + 102400000);
  int* cur    = (int*)(ws + 102600064);
  int* esrc   = (int*)(ws + 102800128);
  int* deg    = (int*)(ws + 106000128);
  int* bsum   = (int*)(ws + 106200192);
  int* boff   = (int*)(ws + 106201216);
  unsigned short* Wt1   = (unsigned short*)(ws + 106202240);
  unsigned short* Wt2   = (unsigned short*)(ws + 106333312);
  float*          bcat1 = (float*)(ws + 106366080);
  float*          bcat2 = (float*)(ws + 106368128);
  float*          ACC   = (float*)(ws + 106368640);

  float* out = (float*)d_out;

  hipMemsetAsync(deg, 0, (size_t)N * sizeof(int), stream);
  hipMemsetAsync(ACC, 0, 32 * sizeof(float), stream);

  dim3 blk(256);

  // ---- CSR build ----
  deg_count<<<dim3((E + 255) / 256), blk, 0, stream>>>(ei, deg, E);
  scan_part<<<dim3(NB), blk, 0, stream>>>(deg, bsum, N);
  scan_tops<<<dim3(1), blk, 0, stream>>>(bsum, boff, rowptr, NB, N);
  scan_final<<<dim3(NB), blk, 0, stream>>>(deg, boff, rowptr, cur, N);
  scatter_edges<<<dim3((E + 255) / 256), blk, 0, stream>>>(ei, cur, esrc, E);

  // ---- prep ----
  cast_bf16<<<dim3((N * 128 / 4 + 255) / 256), blk, 0, stream>>>(x, xb, N * 128 / 4);
  concat_wt<<<dim3((512 * 128 + 255) / 256), blk, 0, stream>>>(
      Wq1, Wk1, Wv1, Ws1, bq1, bk1, bv1, bs1, Wt1, bcat1, 128, 128);
  concat_wt<<<dim3((128 * 128 + 255) / 256), blk, 0, stream>>>(
      Wq2, Wk2, Wv2, Ws2, bq2, bk2, bv2, bs2, Wt2, bcat2, 128, 32);

  // ---- conv1 MFMA linears ----
  mfma_linear<0><<<dim3((N + 127) / 128, 4), blk, 0, stream>>>(
      xb, Wt1, bcat1, Q1, KV1, SK1, (float*)nullptr, N);

  // ---- conv1 fused attention + skip + relu -> bf16 ----
  node_attn1<<<dim3((N * 64 + 255) / 256), blk, 0, stream>>>(rowptr, esrc, Q1, KV1, SK1, H1b, N);

  // ---- conv2 MFMA linears ----
  mfma_linear<1><<<dim3((N + 127) / 128, 1), blk, 0, stream>>>(
      H1b, Wt2, bcat2, Q2, KV2, (unsigned short*)nullptr, H2, N);

  // ---- conv2 fused attention ----
  node_attn2<<<dim3((N * 32 + 255) / 256), blk, 0, stream>>>(rowptr, esrc, Q2, KV2, H2, N);

  // ---- relu + mean + final linear ----
  mean_reduce<<<dim3(1024), blk, 0, stream>>>(H2, ACC, N * 32);
  final_out<<<dim3(1), dim3(64), 0, stream>>>(ACC, Wo, bo, out, 1.0f / (float)N);
}